// Round 8
// baseline (603.288 us; speedup 1.0000x reference)
//
#include <hip/hip_runtime.h>

typedef __attribute__((ext_vector_type(4))) float f4;
typedef __attribute__((ext_vector_type(4))) float f32x4;
typedef _Float16 half8 __attribute__((ext_vector_type(8)));

#define DEVI static __device__ __forceinline__

DEVI void gload_lds16(const void* g, void* l) {
  __builtin_amdgcn_global_load_lds(
      (const __attribute__((address_space(1))) void*)g,
      (__attribute__((address_space(3))) void*)l, 16, 0, 0);
}

DEVI unsigned int pack2(_Float16 a, _Float16 b) {
  unsigned short ua = __builtin_bit_cast(unsigned short, a);
  unsigned short ub = __builtin_bit_cast(unsigned short, b);
  return (unsigned int)ua | ((unsigned int)ub << 16);
}

// bijective XCD swizzle (m204)
DEVI int xcd_swz(int id, int n) {
  int q = n >> 3, r = n & 7;
  int x = id & 7, c = id >> 3;
  return (x < r ? x * (q + 1) : r * (q + 1) + (x - r) * q) + c;
}

#define FENCED_BARRIER()                \
  __builtin_amdgcn_sched_barrier(0);    \
  __builtin_amdgcn_s_barrier();         \
  __builtin_amdgcn_sched_barrier(0);

// ---------------------------------------------------------------------------
// fp32 -> fp16 conversions.
// cvt_plain: H[i]=h(x).  cvt_ileave: H[2i]=(hi), H[2i+1]=(lo residual).
// cvt_dup: H[2i]=H[2i+1]=h(x).
// ---------------------------------------------------------------------------
__global__ __launch_bounds__(256) void cvt_plain(const float* __restrict__ X,
                                                 _Float16* __restrict__ H,
                                                 int n4) {
  int i = blockIdx.x * 256 + threadIdx.x;
  const int stride = gridDim.x * 256;
  typedef _Float16 half4v __attribute__((ext_vector_type(4)));
  for (; i < n4; i += stride) {
    f4 x = ((const f4*)X)[i];
    half4v h;
#pragma unroll
    for (int j = 0; j < 4; ++j) h[j] = (_Float16)x[j];
    ((half4v*)H)[i] = h;
  }
}

template <int DUP>  // 0: (hi,lo) interleave; 1: (h,h) duplicate
__global__ __launch_bounds__(256) void cvt_wide(const float* __restrict__ X,
                                                _Float16* __restrict__ H,
                                                int n4) {
  int i = blockIdx.x * 256 + threadIdx.x;
  const int stride = gridDim.x * 256;
  for (; i < n4; i += stride) {
    f4 x = ((const f4*)X)[i];
    half8 o;
#pragma unroll
    for (int j = 0; j < 4; ++j) {
      _Float16 h = (_Float16)x[j];
      o[2 * j] = h;
      o[2 * j + 1] = DUP ? h : (_Float16)(x[j] - (float)h);
    }
    ((half8*)H)[i] = o;
  }
}

// ---------------------------------------------------------------------------
// Counted-vmcnt ring-3 GEMM core. 512 thr / 8 waves; tile AR x BR, BK=32
// (virtual K for interleaved/dup operands). Wave tile 64x64, 16 MFMA/step.
// Schedule (ledger-verified, one barrier/step, T3+T4):
//   STAGE(0); STAGE(1);
//   for t in [0,NS-1): { vmcnt(3); barrier; STAGE(t+2); COMPUTE(t); }
//   vmcnt(0); barrier; COMPUTE(NS-1);
// - vmcnt(3) leaves stage(t+1)'s 3 loads in flight across the barrier.
// - STAGE(t+2) writes buf (t+2)%3, whose last readers (COMPUTE(t-1)) finished
//   before this barrier (ds_reads consumed by MFMA lgkm waits).
// - Tail: last iter must drain to 0 (only stage(NS-1) outstanding).
// LDS XOR-swizzle on both global source granule and ds_read (T2).
// ---------------------------------------------------------------------------
template <int AR, int BR>
DEVI void core(const _Float16* __restrict__ A0, const _Float16* __restrict__ B0,
               int lda, int ldb, int NS, _Float16* lds, f32x4 (&acc)[4][4]) {
  constexpr int WN = BR / 64;
  constexpr int ACH = AR * 32;
  constexpr int CHUNK = (AR + BR) * 32;
  const int tid = threadIdx.x;
  const int w = tid >> 6, lane = tid & 63;
  const int wm = w / WN, wn = w % WN;
  const int r16 = lane & 15, kg = lane >> 4;

  auto STAGE = [&](int t, int buf) {
    _Float16* base = lds + buf * CHUNK;
#pragma unroll
    for (int j = 0; j < AR / 128; ++j) {
      int g = j * 512 + tid;
      int row = g >> 2, c = g & 3;
      int cs = (c ^ (row >> 1)) & 3;
      gload_lds16(A0 + (size_t)row * lda + t * 32 + cs * 8,
                  base + (j * 512 + w * 64) * 8);
    }
    _Float16* bb = base + ACH;
#pragma unroll
    for (int j = 0; j < BR / 128; ++j) {
      int g = j * 512 + tid;
      int row = g >> 2, c = g & 3;
      int cs = (c ^ (row >> 1)) & 3;
      gload_lds16(B0 + (size_t)row * ldb + t * 32 + cs * 8,
                  bb + (j * 512 + w * 64) * 8);
    }
  };

  auto COMPUTE = [&](int buf) {
    const _Float16* la = lds + buf * CHUNK;
    const _Float16* lb = la + ACH;
    half8 a[4], b[4];
#pragma unroll
    for (int mi = 0; mi < 4; ++mi) {
      int row = wm * 64 + mi * 16 + r16;
      a[mi] = *(const half8*)(la + row * 32 + (((kg ^ (row >> 1)) & 3) * 8));
    }
#pragma unroll
    for (int ni = 0; ni < 4; ++ni) {
      int row = wn * 64 + ni * 16 + r16;
      b[ni] = *(const half8*)(lb + row * 32 + (((kg ^ (row >> 1)) & 3) * 8));
    }
    __builtin_amdgcn_s_setprio(1);
#pragma unroll
    for (int mi = 0; mi < 4; ++mi)
#pragma unroll
      for (int ni = 0; ni < 4; ++ni)
        acc[mi][ni] = __builtin_amdgcn_mfma_f32_16x16x32_f16(
            a[mi], b[ni], acc[mi][ni], 0, 0, 0);
    __builtin_amdgcn_s_setprio(0);
  };

  STAGE(0, 0);
  STAGE(1, 1);
  int t = 0;
  for (; t < NS - 1; ++t) {
    asm volatile("s_waitcnt vmcnt(3)" ::: "memory");  // stage(t) landed
    FENCED_BARRIER();
    if (t + 2 < NS) STAGE(t + 2, (t + 2) % 3);
    COMPUTE(t % 3);
  }
  asm volatile("s_waitcnt vmcnt(0)" ::: "memory");  // tail: drain stage(NS-1)
  FENCED_BARRIER();
  COMPUTE(t % 3);
}

DEVI void acc_zero(f32x4 (&acc)[4][4]) {
#pragma unroll
  for (int i = 0; i < 4; ++i)
#pragma unroll
    for (int j = 0; j < 4; ++j) acc[i][j] = (f32x4)0.0f;
}

// ---------------------------------------------------------------------------
// Engines (512 thr / 8 waves, wave tile 64x64, 72KB LDS ring).
// ---------------------------------------------------------------------------
// Q/K projection (tile 256x128): C = Xi(interleaved hi/lo) * Wd(dup)^T + bias
// over virtual K=2048. OUTMODE 0: write Qi pack(h,lo). 1: write Kd pack(h,h).
template <int OUTMODE>
__global__ __launch_bounds__(512, 4) void proj_eng(
    const _Float16* __restrict__ Xi, const _Float16* __restrict__ Wd,
    const float* __restrict__ bias, unsigned int* __restrict__ OutU) {
  extern __shared__ _Float16 lds[];
  const int id = xcd_swz(blockIdx.x, gridDim.x);
  const int m0 = (id >> 3) * 256, n0 = (id & 7) * 128;
  f32x4 acc[4][4];
  acc_zero(acc);
  core<256, 128>(Xi + (size_t)m0 * 2048, Wd + (size_t)n0 * 2048, 2048, 2048,
                 64, lds, acc);
  const int tid = threadIdx.x;
  const int w = tid >> 6, lane = tid & 63;
  const int wm = w >> 1, wn = w & 1;
  const int r16 = lane & 15, kg = lane >> 4;
  float bcol[4];
#pragma unroll
  for (int ni = 0; ni < 4; ++ni) bcol[ni] = bias[n0 + wn * 64 + ni * 16 + r16];
#pragma unroll
  for (int mi = 0; mi < 4; ++mi) {
    int row = m0 + wm * 64 + mi * 16 + kg * 4;
#pragma unroll
    for (int ni = 0; ni < 4; ++ni) {
      int col = n0 + wn * 64 + ni * 16 + r16;
#pragma unroll
      for (int j = 0; j < 4; ++j) {
        float v = acc[mi][ni][j] + bcol[ni];
        _Float16 h = (_Float16)v;
        _Float16 x2 = OUTMODE ? h : (_Float16)(v - (float)h);
        OutU[(size_t)(row + j) * 1024 + col] = pack2(h, x2);
      }
    }
  }
}

// V projection (tile 256x128, plain fp16 both sides, real K=1024)
// + transposed store Vt[b][d][s].
__global__ __launch_bounds__(512, 4) void proj_eng_v(
    const _Float16* __restrict__ X, const _Float16* __restrict__ Wh,
    const float* __restrict__ bias, _Float16* __restrict__ Vt) {
  extern __shared__ _Float16 lds[];
  const int id = xcd_swz(blockIdx.x, gridDim.x);
  const int m0 = (id >> 3) * 256, n0 = (id & 7) * 128;
  f32x4 acc[4][4];
  acc_zero(acc);
  core<256, 128>(X + (size_t)m0 * 1024, Wh + (size_t)n0 * 1024, 1024, 1024, 32,
                 lds, acc);
  const int tid = threadIdx.x;
  const int w = tid >> 6, lane = tid & 63;
  const int wm = w >> 1, wn = w & 1;
  const int r16 = lane & 15, kg = lane >> 4;
  float bcol[4];
#pragma unroll
  for (int ni = 0; ni < 4; ++ni) bcol[ni] = bias[n0 + wn * 64 + ni * 16 + r16];
  __syncthreads();  // ring done; reuse LDS as transpose buffer (64KB)
  _Float16(*T)[256] = (_Float16(*)[256])lds;
#pragma unroll
  for (int mi = 0; mi < 4; ++mi) {
    int ml = wm * 64 + mi * 16 + kg * 4;
#pragma unroll
    for (int ni = 0; ni < 4; ++ni) {
      int nl = wn * 64 + ni * 16 + r16;
#pragma unroll
      for (int j = 0; j < 4; ++j)
        T[nl][ml + j] = (_Float16)(acc[mi][ni][j] + bcol[ni]);
    }
  }
  __syncthreads();
  const int b = m0 >> 11;
  const int s0 = m0 & 2047;
#pragma unroll
  for (int r = 0; r < 8; ++r) {
    int flat = tid + r * 512;
    int n = flat >> 5, c = flat & 31;
    half8 v = *(const half8*)&T[n][c * 8];
    *(half8*)(Vt + (size_t)b * (1024 * 2048) + (size_t)(n0 + n) * 2048 + s0 +
              c * 8) = v;
  }
}

// QK^T (tile 128x256): L = Qi . Kd^T over virtual K=2048 (== (Qh+Ql).K exact)
__global__ __launch_bounds__(512, 4) void qk_eng(
    const _Float16* __restrict__ Qi, const _Float16* __restrict__ Kd,
    float* __restrict__ Lg, int bbase) {
  extern __shared__ _Float16 lds[];
  const int id = xcd_swz(blockIdx.x, gridDim.x);
  const int y = id / 72;
  int t = id % 72;
  int qt = 0, base = 0;
  while (t >= base + (qt >> 1) + 1) { base += (qt >> 1) + 1; ++qt; }
  const int kt = t - base;
  const int b = bbase + y;
  f32x4 acc[4][4];
  acc_zero(acc);
  core<128, 256>(Qi + ((size_t)b * 2048 + qt * 128) * 2048,
                 Kd + ((size_t)b * 2048 + kt * 256) * 2048, 2048, 2048, 64,
                 lds, acc);
  const int tid = threadIdx.x;
  const int w = tid >> 6, lane = tid & 63;
  const int wm = w >> 2, wn = w & 3;
  const int r16 = lane & 15, kg = lane >> 4;
  float* L = Lg + (size_t)y * (2048 * 2048);
#pragma unroll
  for (int mi = 0; mi < 4; ++mi) {
    int row = qt * 128 + wm * 64 + mi * 16 + kg * 4;
#pragma unroll
    for (int ni = 0; ni < 4; ++ni) {
      int col = kt * 256 + wn * 64 + ni * 16 + r16;
#pragma unroll
      for (int j = 0; j < 4; ++j)
        L[(size_t)(row + j) * 2048 + col] = acc[mi][ni][j];
    }
  }
}

// PV (tile 128x256): Out = P . Vt^T, causal K limit per q-tile (real K).
__global__ __launch_bounds__(512, 4) void pv_eng(
    const float* __restrict__ Lg, const _Float16* __restrict__ Vt,
    float* __restrict__ Out, int bbase) {
  extern __shared__ _Float16 lds[];
  const int id = xcd_swz(blockIdx.x, gridDim.x);
  const int y = id >> 6;
  const int qt = (id & 63) >> 2, nt = id & 3;
  const int b = bbase + y;
  const _Float16* P = (const _Float16*)(Lg + (size_t)y * (2048 * 2048));
  f32x4 acc[4][4];
  acc_zero(acc);
  core<128, 256>(P + (size_t)(qt * 128) * 4096,
                 Vt + (size_t)b * (1024 * 2048) + (size_t)(nt * 256) * 2048,
                 4096, 2048, ((qt >> 1) + 1) * 8, lds, acc);
  const int tid = threadIdx.x;
  const int w = tid >> 6, lane = tid & 63;
  const int wm = w >> 2, wn = w & 3;
  const int r16 = lane & 15, kg = lane >> 4;
#pragma unroll
  for (int mi = 0; mi < 4; ++mi) {
    int row = qt * 128 + wm * 64 + mi * 16 + kg * 4;
#pragma unroll
    for (int ni = 0; ni < 4; ++ni) {
      int col = nt * 256 + wn * 64 + ni * 16 + r16;
#pragma unroll
      for (int j = 0; j < 4; ++j)
        Out[(size_t)(b * 2048 + row + j) * 1024 + col] = acc[mi][ni][j];
    }
  }
}

// ---------------------------------------------------------------------------
// Legacy fp32-staging projection (fallback for small ws): in-kernel X split,
// writes Qi (OUTMODE 0) or Kd (OUTMODE 1) directly. Validated structure (r2).
// ---------------------------------------------------------------------------
template <int OUTMODE>
__global__ __launch_bounds__(256) void proj_legacy(
    const float* __restrict__ X, const float* __restrict__ W,
    const float* __restrict__ bias, unsigned int* __restrict__ OutU) {
  __shared__ struct {
    float As[128][36];
    float Bs[128][36];
  } u;
  const int tid = threadIdx.x;
  const int lane = tid & 63, w = tid >> 6;
  const int wm = w >> 1, wn = w & 1;
  const int r16 = lane & 15, kg = lane >> 4;
  const int m0 = blockIdx.y * 128, n0 = blockIdx.x * 128;
  f32x4 acc[4][4];
  acc_zero(acc);
  f4 ra[4], rb[4];
  auto LOAD = [&](int kt) {
#pragma unroll
    for (int r = 0; r < 4; ++r) {
      int flat = tid + r * 256;
      int row = flat >> 3, c = flat & 7;
      ra[r] = *(const f4*)(X + (size_t)(m0 + row) * 1024 + kt * 32 + c * 4);
      rb[r] = *(const f4*)(W + (size_t)(n0 + row) * 1024 + kt * 32 + c * 4);
    }
  };
  LOAD(0);
  for (int kt = 0; kt < 32; ++kt) {
    __syncthreads();
#pragma unroll
    for (int r = 0; r < 4; ++r) {
      int flat = tid + r * 256;
      int row = flat >> 3, c = flat & 7;
      *(f4*)&u.As[row][c * 4] = ra[r];
      *(f4*)&u.Bs[row][c * 4] = rb[r];
    }
    __syncthreads();
    if (kt + 1 < 32) LOAD(kt + 1);
    half8 ah[4], al[4], bh[4];
#pragma unroll
    for (int mi = 0; mi < 4; ++mi) {
      const float* p = &u.As[wm * 64 + mi * 16 + r16][kg * 8];
      f4 x0 = *(const f4*)p, x1 = *(const f4*)(p + 4);
      half8 h, l;
#pragma unroll
      for (int j = 0; j < 4; ++j) {
        h[j] = (_Float16)x0[j];
        h[j + 4] = (_Float16)x1[j];
        l[j] = (_Float16)(x0[j] - (float)h[j]);
        l[j + 4] = (_Float16)(x1[j] - (float)h[j + 4]);
      }
      ah[mi] = h;
      al[mi] = l;
    }
#pragma unroll
    for (int ni = 0; ni < 4; ++ni) {
      const float* p = &u.Bs[wn * 64 + ni * 16 + r16][kg * 8];
      f4 x0 = *(const f4*)p, x1 = *(const f4*)(p + 4);
      half8 h;
#pragma unroll
      for (int j = 0; j < 4; ++j) {
        h[j] = (_Float16)x0[j];
        h[j + 4] = (_Float16)x1[j];
      }
      bh[ni] = h;
    }
#pragma unroll
    for (int mi = 0; mi < 4; ++mi)
#pragma unroll
      for (int ni = 0; ni < 4; ++ni) {
        acc[mi][ni] = __builtin_amdgcn_mfma_f32_16x16x32_f16(
            ah[mi], bh[ni], acc[mi][ni], 0, 0, 0);
        acc[mi][ni] = __builtin_amdgcn_mfma_f32_16x16x32_f16(
            al[mi], bh[ni], acc[mi][ni], 0, 0, 0);
      }
  }
  float bcol[4];
#pragma unroll
  for (int ni = 0; ni < 4; ++ni) bcol[ni] = bias[n0 + wn * 64 + ni * 16 + r16];
#pragma unroll
  for (int mi = 0; mi < 4; ++mi) {
    int row = m0 + wm * 64 + mi * 16 + kg * 4;
#pragma unroll
    for (int ni = 0; ni < 4; ++ni) {
      int col = n0 + wn * 64 + ni * 16 + r16;
#pragma unroll
      for (int j = 0; j < 4; ++j) {
        float v = acc[mi][ni][j] + bcol[ni];
        _Float16 h = (_Float16)v;
        _Float16 x2 = OUTMODE ? h : (_Float16)(v - (float)h);
        OutU[(size_t)(row + j) * 1024 + col] = pack2(h, x2);
      }
    }
  }
}

// ---------------------------------------------------------------------------
// Row softmax; in-place fp16 P (row stride 4096 halves); zero-fill to 256-col
// tile boundary.
// ---------------------------------------------------------------------------
__global__ __launch_bounds__(256) void softmax_kernel(
    float* __restrict__ Lg, const int* __restrict__ pad, int bbase) {
  const int q = blockIdx.x;
  const int y = blockIdx.y;
  const int b = bbase + y;
  const int tid = threadIdx.x;
  float* row = Lg + (size_t)y * (2048 * 2048) + (size_t)q * 2048;
  _Float16* prow = (_Float16*)row;
  const int* pb = pad + (size_t)b * 2048;
  const int kend = ((q >> 8) + 1) << 8;
  float v[8];
  int nv = 0;
  float mx = -3.0e38f;
  for (int k = tid; k <= q; k += 256) {
    float l = row[k];
    if (pb[k] == 0) l += -1.0e9f;
    v[nv++] = l;
    mx = fmaxf(mx, l);
  }
  __shared__ float red[4];
  for (int o = 32; o; o >>= 1) mx = fmaxf(mx, __shfl_xor(mx, o));
  if ((tid & 63) == 0) red[tid >> 6] = mx;
  __syncthreads();
  mx = fmaxf(fmaxf(red[0], red[1]), fmaxf(red[2], red[3]));
  __syncthreads();
  float s = 0.f;
  for (int i = 0; i < nv; ++i) s += expf(v[i] - mx);
  for (int o = 32; o; o >>= 1) s += __shfl_xor(s, o);
  if ((tid & 63) == 0) red[tid >> 6] = s;
  __syncthreads();
  s = red[0] + red[1] + red[2] + red[3];
  const float inv = 1.0f / s;
  int i = 0;
  for (int k = tid; k <= q; k += 256) {
    prow[k] = (_Float16)(expf(v[i] - mx) * inv);
    ++i;
  }
  for (int k = q + 1 + tid; k < kend; k += 256) prow[k] = (_Float16)0.0f;
}

// ---------------------------------------------------------------------------
// Fixup for degenerate rows q < f[b] (validated rounds 4-7).
// ---------------------------------------------------------------------------
__global__ __launch_bounds__(512) void fix_f(const int* __restrict__ pad,
                                             int* __restrict__ fb) {
  const int b = threadIdx.x >> 6, k = threadIdx.x & 63;
  unsigned long long m = __ballot(pad[b * 2048 + k] != 0);
  if (k == 0) fb[b] = m ? (__ffsll((long long)m) - 1) : 64;
}

__global__ __launch_bounds__(256) void fix_qrow2(
    const float* __restrict__ xQ, const float* __restrict__ Wq,
    const float* __restrict__ bq, const int* __restrict__ fb,
    float* __restrict__ Qrow) {
  const int b = blockIdx.y;
  const int f = fb[b];
  const int tid = threadIdx.x;
  const int e = blockIdx.x * 16 + (tid >> 4);
  const int l16 = tid & 15;
  __shared__ float xq[1024];
  for (int q = 0; q < f; ++q) {
    *(f4*)&xq[tid * 4] = ((const f4*)(xQ + (size_t)(b * 2048 + q) * 1024))[tid];
    __syncthreads();
    float a = 0.f;
#pragma unroll
    for (int it = 0; it < 16; ++it) {
      int d = l16 * 4 + it * 64;
      f4 ww = *(const f4*)(Wq + (size_t)e * 1024 + d);
      a += xq[d] * ww[0] + xq[d + 1] * ww[1] + xq[d + 2] * ww[2] +
           xq[d + 3] * ww[3];
    }
    for (int o = 8; o; o >>= 1) a += __shfl_xor(a, o);
    if (l16 == 0) Qrow[((size_t)b * 64 + q) * 1024 + e] = a + bq[e];
    __syncthreads();
  }
}

__global__ __launch_bounds__(256) void fix_qb0(const float* __restrict__ bk,
                                               const int* __restrict__ fb,
                                               const float* __restrict__ Qrow,
                                               float* __restrict__ qb0) {
  const int q = blockIdx.x, b = blockIdx.y;
  if (q >= fb[b]) return;
  const int tid = threadIdx.x;
  const float* qr = Qrow + ((size_t)b * 64 + q) * 1024;
  float p = 0.f;
  for (int e = tid; e < 1024; e += 256) p += qr[e] * bk[e];
  __shared__ float red[4];
  for (int o = 32; o; o >>= 1) p += __shfl_xor(p, o);
  if ((tid & 63) == 0) red[tid >> 6] = p;
  __syncthreads();
  if (tid == 0) qb0[b * 64 + q] = red[0] + red[1] + red[2] + red[3];
}

__global__ __launch_bounds__(256) void fix_g2(const float* __restrict__ Wk,
                                              const int* __restrict__ fb,
                                              const float* __restrict__ Qrow,
                                              float* __restrict__ Gpart) {
  const int b = blockIdx.y;
  const int f = fb[b];
  const int tid = threadIdx.x;
  const int ddblk = blockIdx.x & 3, es = blockIdx.x >> 2;
  const int dd = ddblk * 256 + tid;
  __shared__ float qc[128];
  for (int q = 0; q < f; ++q) {
    if (tid < 32)
      *(f4*)&qc[tid * 4] =
          ((const f4*)(Qrow + ((size_t)b * 64 + q) * 1024 + es * 128))[tid];
    __syncthreads();
    float g = 0.f;
    for (int e = 0; e < 128; ++e)
      g += qc[e] * Wk[(size_t)(es * 128 + e) * 1024 + dd];
    Gpart[(((size_t)es * 8 + b) * 64 + q) * 1024 + dd] = g;
    __syncthreads();
  }
}

__global__ __launch_bounds__(256) void fix_logit2(
    const float* __restrict__ xK, const int* __restrict__ pad,
    const int* __restrict__ fb, const float* __restrict__ Gpart,
    const float* __restrict__ qb0, float* __restrict__ lrow) {
  const int b = blockIdx.y;
  const int f = fb[b];
  const int tid = threadIdx.x;
  const int k = blockIdx.x * 16 + (tid >> 4);
  const int l16 = tid & 15;
  __shared__ float Gs[1024];
  for (int q = 0; q < f; ++q) {
    f4 s = (f4)0.0f;
#pragma unroll
    for (int es = 0; es < 8; ++es)
      s += ((const f4*)(Gpart + (((size_t)es * 8 + b) * 64 + q) * 1024))[tid];
    *(f4*)&Gs[tid * 4] = s;
    __syncthreads();
    float a = 0.f;
#pragma unroll
    for (int it = 0; it < 16; ++it) {
      int d = l16 * 4 + it * 64;
      f4 x = *(const f4*)(xK + (size_t)(b * 2048 + k) * 1024 + d);
      a += x[0] * Gs[d] + x[1] * Gs[d + 1] + x[2] * Gs[d + 2] +
           x[3] * Gs[d + 3];
    }
    for (int o = 8; o; o >>= 1) a += __shfl_xor(a, o);
    if (l16 == 0) {
      float l = a + qb0[b * 64 + q];
      if (pad[b * 2048 + k] == 0) l += -1.0e9f;
      if (k > q) l += -1.0e9f;
      lrow[((size_t)b * 64 + q) * 2048 + k] = l;
    }
    __syncthreads();
  }
}

__global__ __launch_bounds__(256) void fix_sm(const int* __restrict__ fb,
                                              float* __restrict__ lrow,
                                              float* __restrict__ srow) {
  const int q = blockIdx.x, b = blockIdx.y;
  if (q >= fb[b]) return;
  const int tid = threadIdx.x;
  float* row = lrow + ((size_t)b * 64 + q) * 2048;
  float v[8];
  float mx = -3.0e38f;
#pragma unroll
  for (int i = 0; i < 8; ++i) {
    v[i] = row[tid + i * 256];
    mx = fmaxf(mx, v[i]);
  }
  __shared__ float red[4];
  for (int o = 32; o; o >>= 1) mx = fmaxf(mx, __shfl_xor(mx, o));
  if ((tid & 63) == 0) red[tid >> 6] = mx;
  __syncthreads();
  mx = fmaxf(fmaxf(red[0], red[1]), fmaxf(red[2], red[3]));
  __syncthreads();
  float s = 0.f;
#pragma unroll
  for (int i = 0; i < 8; ++i) {
    v[i] = expf(v[i] - mx);
    s += v[i];
  }
#pragma unroll
  for (int i = 0; i < 8; ++i) row[tid + i * 256] = v[i];
  for (int o = 32; o; o >>= 1) s += __shfl_xor(s, o);
  if ((tid & 63) == 0) red[tid >> 6] = s;
  __syncthreads();
  if (tid == 0) srow[b * 64 + q] = red[0] + red[1] + red[2] + red[3];
}

__global__ __launch_bounds__(256) void fix_pv2(
    const _Float16* __restrict__ Vt, const int* __restrict__ fb,
    const float* __restrict__ lrow, const float* __restrict__ srow,
    float* __restrict__ Out) {
  const int b = blockIdx.y;
  const int f = fb[b];
  const int tid = threadIdx.x;
  const int d = blockIdx.x * 16 + (tid >> 4);
  const int l16 = tid & 15;
  __shared__ float ps[2048];
  for (int q = 0; q < f; ++q) {
    const f4* src = (const f4*)(lrow + ((size_t)b * 64 + q) * 2048);
    *(f4*)&ps[tid * 8] = src[tid * 2];
    *(f4*)&ps[tid * 8 + 4] = src[tid * 2 + 1];
    __syncthreads();
    float o = 0.f;
#pragma unroll
    for (int it = 0; it < 16; ++it) {
      int k = l16 * 8 + it * 128;
      half8 vv = *(const half8*)(Vt + (size_t)b * (1024 * 2048) +
                                 (size_t)d * 2048 + k);
      o += (float)vv[0] * ps[k] + (float)vv[1] * ps[k + 1] +
           (float)vv[2] * ps[k + 2] + (float)vv[3] * ps[k + 3] +
           (float)vv[4] * ps[k + 4] + (float)vv[5] * ps[k + 5] +
           (float)vv[6] * ps[k + 6] + (float)vv[7] * ps[k + 7];
    }
    for (int of = 8; of; of >>= 1) o += __shfl_xor(o, of);
    if (l16 == 0)
      Out[(size_t)(b * 2048 + q) * 1024 + d] = o * (1.0f / srow[b * 64 + q]);
    __syncthreads();
  }
}

// ---------------------------------------------------------------------------
extern "C" void kernel_launch(void* const* d_in, const int* in_sizes, int n_in,
                              void* d_out, int out_size, void* d_ws,
                              size_t ws_size, hipStream_t stream) {
  const float* xQ = (const float*)d_in[0];
  const float* xK = (const float*)d_in[1];
  const float* xV = (const float*)d_in[2];
  const int* pad = (const int*)d_in[3];
  const float* Wq = (const float*)d_in[5];
  const float* bq = (const float*)d_in[6];
  const float* Wk = (const float*)d_in[7];
  const float* bk = (const float*)d_in[8];
  const float* Wv = (const float*)d_in[9];
  const float* bv = (const float*)d_in[10];
  float* Out = (float*)d_out;

  const size_t MB = (size_t)1 << 20;
  char* wsb = (char*)d_ws;
  // Persistent: Qi [0,64) interleaved hi/lo; Kd [64,128) dup; Vt [128,160).
  _Float16* Qi = (_Float16*)(wsb);
  _Float16* Kd = (_Float16*)(wsb + 64 * MB);
  _Float16* Vt = (_Float16*)(wsb + 128 * MB);
  float* Lg = (float*)(wsb + 160 * MB);

  size_t avail = (ws_size > 160 * MB) ? ws_size - 160 * MB : 0;
  int G = (int)(avail / (16 * MB));
  if (G > 8) G = 8;
  if (G < 1) G = 1;

  const int SMEM = 73728;  // 3 x 24KB ring
  (void)hipFuncSetAttribute((const void*)&proj_eng<0>,
                            hipFuncAttributeMaxDynamicSharedMemorySize, SMEM);
  (void)hipFuncSetAttribute((const void*)&proj_eng<1>,
                            hipFuncAttributeMaxDynamicSharedMemorySize, SMEM);
  (void)hipFuncSetAttribute((const void*)&proj_eng_v,
                            hipFuncAttributeMaxDynamicSharedMemorySize, SMEM);
  (void)hipFuncSetAttribute((const void*)&qk_eng,
                            hipFuncAttributeMaxDynamicSharedMemorySize, SMEM);
  (void)hipFuncSetAttribute((const void*)&pv_eng,
                            hipFuncAttributeMaxDynamicSharedMemorySize, SMEM);

  dim3 blk(256), eblk(512);
  const bool fast = (ws_size >= 228 * MB);

  // --- V projection: sX@[0,32) sW@[32,34) (inside unwritten Qi region) ---
  {
    _Float16* sX = (_Float16*)(wsb);
    _Float16* sW = (_Float16*)(wsb + 32 * MB);
    cvt_plain<<<dim3(2048), blk, 0, stream>>>(xV, sX, 4194304);
    cvt_plain<<<dim3(1024), blk, 0, stream>>>(Wv, sW, 262144);
    proj_eng_v<<<dim3(512), eblk, SMEM, stream>>>(sX, sW, bv, Vt);
  }
  if (fast) {
    // --- K proj: XiK@[0,64) (Qi region), WdK@[160,164) (Lg region) ---
    _Float16* XiK = (_Float16*)(wsb);
    _Float16* WdK = (_Float16*)(wsb + 160 * MB);
    cvt_wide<0><<<dim3(2048), blk, 0, stream>>>(xK, XiK, 4194304);
    cvt_wide<1><<<dim3(1024), blk, 0, stream>>>(Wk, WdK, 262144);
    proj_eng<1><<<dim3(512), eblk, SMEM, stream>>>(XiK, WdK, bk,
                                                   (unsigned int*)Kd);
    // --- Q proj: XiQ@[160,224), WdQ@[224,228); writes Qi@[0,64) ---
    _Float16* XiQ = (_Float16*)(wsb + 160 * MB);
    _Float16* WdQ = (_Float16*)(wsb + 224 * MB);
    cvt_wide<0><<<dim3(2048), blk, 0, stream>>>(xQ, XiQ, 4194304);
    cvt_wide<1><<<dim3(1024), blk, 0, stream>>>(Wq, WdQ, 262144);
    proj_eng<0><<<dim3(512), eblk, SMEM, stream>>>(XiQ, WdQ, bq,
                                                   (unsigned int*)Qi);
  } else {
    proj_legacy<1><<<dim3(8, 128), blk, 0, stream>>>(xK, Wk, bk,
                                                     (unsigned int*)Kd);
    proj_legacy<0><<<dim3(8, 128), blk, 0, stream>>>(xQ, Wq, bq,
                                                     (unsigned int*)Qi);
  }

  // --- Attention ---
  for (int bbase = 0; bbase < 8; bbase += G) {
    int nb = (8 - bbase < G) ? (8 - bbase) : G;
    qk_eng<<<dim3(72 * nb), eblk, SMEM, stream>>>(Qi, Kd, Lg, bbase);
    softmax_kernel<<<dim3(2048, nb), blk, 0, stream>>>(Lg, pad, bbase);
    pv_eng<<<dim3(64 * nb), eblk, SMEM, stream>>>(Lg, Vt, Out, bbase);
  }

  // --- Fixup: scratch in [0,24) MB (Qi dead after last qk) ---
  int* fb = (int*)(wsb);
  float* qb0 = (float*)(wsb + 4 * 1024);
  float* srow = (float*)(wsb + 8 * 1024);
  float* Qrow = (float*)(wsb + 1 * MB);   // 2 MB
  float* Gpart = (float*)(wsb + 4 * MB);  // 16 MB
  float* lrow = (float*)(wsb + 20 * MB);  // 4 MB

  fix_f<<<dim3(1), dim3(512), 0, stream>>>(pad, fb);
  fix_qrow2<<<dim3(64, 8), blk, 0, stream>>>(xQ, Wq, bq, fb, Qrow);
  fix_qb0<<<dim3(64, 8), blk, 0, stream>>>(bk, fb, Qrow, qb0);
  fix_g2<<<dim3(32, 8), blk, 0, stream>>>(Wk, fb, Qrow, Gpart);
  fix_logit2<<<dim3(128, 8), blk, 0, stream>>>(xK, pad, fb, Gpart, qb0, lrow);
  fix_sm<<<dim3(64, 8), blk, 0, stream>>>(fb, lrow, srow);
  fix_pv2<<<dim3(64, 8), blk, 0, stream>>>(Vt, fb, lrow, srow, Out);
}

// Round 9
// 547.467 us; speedup vs baseline: 1.1020x; 1.1020x over previous
//
#include <hip/hip_runtime.h>

typedef __attribute__((ext_vector_type(4))) float f4;
typedef __attribute__((ext_vector_type(4))) float f32x4;
typedef _Float16 half8 __attribute__((ext_vector_type(8)));

#define DEVI static __device__ __forceinline__

DEVI void gload_lds16(const void* g, void* l) {
  __builtin_amdgcn_global_load_lds(
      (const __attribute__((address_space(1))) void*)g,
      (__attribute__((address_space(3))) void*)l, 16, 0, 0);
}

// bijective XCD swizzle (m204)
DEVI int xcd_swz(int id, int n) {
  int q = n >> 3, r = n & 7;
  int x = id & 7, c = id >> 3;
  return (x < r ? x * (q + 1) : r * (q + 1) + (x - r) * q) + c;
}

#define FENCED_BARRIER()                \
  __builtin_amdgcn_sched_barrier(0);    \
  __builtin_amdgcn_s_barrier();         \
  __builtin_amdgcn_sched_barrier(0);

#define SWZ(kgv, rowv) ((((kgv) ^ ((rowv) >> 1)) & 3) * 8)

// ---------------------------------------------------------------------------
// W-side fp32 -> fp16 conversions (tiny, 2MB each).
// ---------------------------------------------------------------------------
__global__ __launch_bounds__(256) void cvt_plain(const float* __restrict__ X,
                                                 _Float16* __restrict__ H,
                                                 int n4) {
  int i = blockIdx.x * 256 + threadIdx.x;
  const int stride = gridDim.x * 256;
  typedef _Float16 half4v __attribute__((ext_vector_type(4)));
  for (; i < n4; i += stride) {
    f4 x = ((const f4*)X)[i];
    half4v h;
#pragma unroll
    for (int j = 0; j < 4; ++j) h[j] = (_Float16)x[j];
    ((half4v*)H)[i] = h;
  }
}

__global__ __launch_bounds__(256) void cvt_split(const float* __restrict__ X,
                                                 _Float16* __restrict__ H,
                                                 _Float16* __restrict__ L,
                                                 int n4) {
  int i = blockIdx.x * 256 + threadIdx.x;
  const int stride = gridDim.x * 256;
  typedef _Float16 half4v __attribute__((ext_vector_type(4)));
  for (; i < n4; i += stride) {
    f4 x = ((const f4*)X)[i];
    half4v h, l;
#pragma unroll
    for (int j = 0; j < 4; ++j) {
      h[j] = (_Float16)x[j];
      l[j] = (_Float16)(x[j] - (float)h[j]);
    }
    ((half4v*)H)[i] = h;
    ((half4v*)L)[i] = l;
  }
}

DEVI void acc_zero44(f32x4 (&acc)[4][4]) {
#pragma unroll
  for (int i = 0; i < 4; ++i)
#pragma unroll
    for (int j = 0; j < 4; ++j) acc[i][j] = (f32x4)0.0f;
}
DEVI void acc_zero42(f32x4 (&acc)[4][2]) {
#pragma unroll
  for (int i = 0; i < 4; ++i)
#pragma unroll
    for (int j = 0; j < 2; ++j) acc[i][j] = (f32x4)0.0f;
}

// ---------------------------------------------------------------------------
// Fused-cvt projection (tile 256x128, 512 thr / 8 waves, 2-buf):
// A side: fp32 X reg-staged + in-kernel fp16 cvt + swizzled ds_write
//   (values bit-identical to pre-converted path: same RNE rounding).
// B side: pre-converted W hi (+lo if WSPLIT) via gload_lds, source-swizzled.
// Schedule per step: WLOAD(t+1)+ALOAD(t+1) issue; COMPUTE(t); vmcnt(0);
// AWRITE(t+1); lgkmcnt(0); barrier.  (A/W writes target buf^1, whose last
// readers finished before the previous barrier — ledger-safe.)
// OUTMODE: 0 = write hi+lo (Q), 1 = hi only (K), 2 = transposed Vt (V).
// ---------------------------------------------------------------------------
template <int WSPLIT, int OUTMODE>
__global__ __launch_bounds__(512, 2) void proj_fused(
    const float* __restrict__ X, const _Float16* __restrict__ Wh,
    const _Float16* __restrict__ Wl, const float* __restrict__ bias,
    _Float16* __restrict__ OutHi, _Float16* __restrict__ OutLo,
    _Float16* __restrict__ VtOut) {
  extern __shared__ _Float16 lds[];
  constexpr int ACH = 256 * 32;
  constexpr int BCH = 128 * 32;
  constexpr int CHUNK = ACH + BCH * (1 + WSPLIT);
  const int id = xcd_swz(blockIdx.x, gridDim.x);
  const int m0 = (id >> 3) * 256, n0 = (id & 7) * 128;
  const float* A = X + (size_t)m0 * 1024;
  const _Float16* B0 = Wh + (size_t)n0 * 1024;
  const _Float16* B1 = Wl + (size_t)n0 * 1024;
  const int tid = threadIdx.x;
  const int w = tid >> 6, lane = tid & 63;
  const int wm = w >> 1, wn = w & 1;
  const int r16 = lane & 15, kg = lane >> 4;
  f32x4 acc[4][4];
  acc_zero44(acc);
  f4 ra[4];

  auto ALOAD = [&](int t) {
#pragma unroll
    for (int j = 0; j < 2; ++j) {
      int g = tid + j * 512;
      int row = g >> 2, c = g & 3;
      const float* src = A + (size_t)row * 1024 + t * 32 + c * 8;
      ra[2 * j] = *(const f4*)src;
      ra[2 * j + 1] = *(const f4*)(src + 4);
    }
  };
  auto AWRITE = [&](int buf) {
    _Float16* ab = lds + buf * CHUNK;
#pragma unroll
    for (int j = 0; j < 2; ++j) {
      int g = tid + j * 512;
      int row = g >> 2, c = g & 3;
      half8 h;
#pragma unroll
      for (int e = 0; e < 4; ++e) {
        h[e] = (_Float16)ra[2 * j][e];
        h[e + 4] = (_Float16)ra[2 * j + 1][e];
      }
      *(half8*)(ab + (size_t)row * 32 + SWZ(c, row)) = h;
    }
  };
  auto WLOAD = [&](int t, int buf) {
    _Float16* bb = lds + buf * CHUNK + ACH;
    int row = tid >> 2, c = tid & 3;
    int cs = (c ^ (row >> 1)) & 3;
    gload_lds16(B0 + (size_t)row * 1024 + t * 32 + cs * 8, bb + tid * 8);
    if (WSPLIT)
      gload_lds16(B1 + (size_t)row * 1024 + t * 32 + cs * 8,
                  bb + BCH + tid * 8);
  };
  auto COMPUTE = [&](int buf) {
    const _Float16* la = lds + buf * CHUNK;
    const _Float16* lb = la + ACH;
    half8 a[4], b0f[4], b1f[4];
#pragma unroll
    for (int mi = 0; mi < 4; ++mi) {
      int row = wm * 64 + mi * 16 + r16;
      a[mi] = *(const half8*)(la + row * 32 + SWZ(kg, row));
    }
#pragma unroll
    for (int ni = 0; ni < 4; ++ni) {
      int row = wn * 64 + ni * 16 + r16;
      int off = row * 32 + SWZ(kg, row);
      b0f[ni] = *(const half8*)(lb + off);
      if (WSPLIT) b1f[ni] = *(const half8*)(lb + BCH + off);
    }
    __builtin_amdgcn_s_setprio(1);
#pragma unroll
    for (int mi = 0; mi < 4; ++mi)
#pragma unroll
      for (int ni = 0; ni < 4; ++ni) {
        acc[mi][ni] = __builtin_amdgcn_mfma_f32_16x16x32_f16(
            a[mi], b0f[ni], acc[mi][ni], 0, 0, 0);
        if (WSPLIT)
          acc[mi][ni] = __builtin_amdgcn_mfma_f32_16x16x32_f16(
              a[mi], b1f[ni], acc[mi][ni], 0, 0, 0);
      }
    __builtin_amdgcn_s_setprio(0);
  };

  const int NS = 32;
  WLOAD(0, 0);
  ALOAD(0);
  asm volatile("s_waitcnt vmcnt(0)" ::: "memory");
  __builtin_amdgcn_sched_barrier(0);
  AWRITE(0);
  asm volatile("s_waitcnt lgkmcnt(0)" ::: "memory");
  FENCED_BARRIER();
  for (int t = 0; t < NS; ++t) {
    if (t + 1 < NS) {
      WLOAD(t + 1, (t + 1) & 1);
      ALOAD(t + 1);
    }
    COMPUTE(t & 1);
    if (t + 1 < NS) {
      asm volatile("s_waitcnt vmcnt(0)" ::: "memory");
      __builtin_amdgcn_sched_barrier(0);
      AWRITE((t + 1) & 1);
      asm volatile("s_waitcnt lgkmcnt(0)" ::: "memory");
      FENCED_BARRIER();
    }
  }

  float bcol[4];
#pragma unroll
  for (int ni = 0; ni < 4; ++ni) bcol[ni] = bias[n0 + wn * 64 + ni * 16 + r16];

  if (OUTMODE != 2) {
#pragma unroll
    for (int mi = 0; mi < 4; ++mi) {
      int row = m0 + wm * 64 + mi * 16 + kg * 4;
#pragma unroll
      for (int ni = 0; ni < 4; ++ni) {
        int col = n0 + wn * 64 + ni * 16 + r16;
#pragma unroll
        for (int j = 0; j < 4; ++j) {
          float v = acc[mi][ni][j] + bcol[ni];
          _Float16 h = (_Float16)v;
          OutHi[(size_t)(row + j) * 1024 + col] = h;
          if (OUTMODE == 0)
            OutLo[(size_t)(row + j) * 1024 + col] = (_Float16)(v - (float)h);
        }
      }
    }
  } else {
    __syncthreads();  // ring done; reuse LDS as transpose buffer (64 KB)
    _Float16(*T)[256] = (_Float16(*)[256])lds;
#pragma unroll
    for (int mi = 0; mi < 4; ++mi) {
      int ml = wm * 64 + mi * 16 + kg * 4;
#pragma unroll
      for (int ni = 0; ni < 4; ++ni) {
        int nl = wn * 64 + ni * 16 + r16;
#pragma unroll
        for (int j = 0; j < 4; ++j)
          T[nl][ml + j] = (_Float16)(acc[mi][ni][j] + bcol[ni]);
      }
    }
    __syncthreads();
    const int b = m0 >> 11;
    const int s0 = m0 & 2047;
#pragma unroll
    for (int r = 0; r < 8; ++r) {
      int flat = tid + r * 512;
      int n = flat >> 5, c = flat & 31;
      half8 v = *(const half8*)&T[n][c * 8];
      *(half8*)(VtOut + (size_t)b * (1024 * 2048) + (size_t)(n0 + n) * 2048 +
                s0 + c * 8) = v;
    }
  }
}

// ---------------------------------------------------------------------------
// QK^T: ring-3 counted-vmcnt engine, tile 64x256 (chunk 24KB, ring 72KB).
// A0=Qh, A1=Ql (hi/lo streams, same MFMA order as validated rounds ->
// bit-identical logits). Schedule (r8-verified structure):
//   STAGE(0);STAGE(1); for t<NS-1 { vmcnt(3); bar; STAGE(t+2); COMPUTE(t); }
//   vmcnt(0); bar; COMPUTE(NS-1).   3 loads/thread/stage -> vmcnt(3).
// ---------------------------------------------------------------------------
__global__ __launch_bounds__(512, 4) void qk_eng(
    const _Float16* __restrict__ Qh, const _Float16* __restrict__ Ql,
    const _Float16* __restrict__ Kh, float* __restrict__ Lg, int bbase) {
  extern __shared__ _Float16 lds[];
  constexpr int CHUNK = 12288;  // A0 2048 | A1 2048 | B 8192 halves
  const int id = xcd_swz(blockIdx.x, gridDim.x);
  const int y = id / 144;
  int t = id % 144;
  int g4 = 0, base = 0;
  while (t >= base + (g4 + 1) * 4) { base += (g4 + 1) * 4; ++g4; }
  const int rem = t - base;
  const int qt = g4 * 4 + rem / (g4 + 1);  // 64-row q tile [0,32)
  const int kt = rem % (g4 + 1);           // 256-col k tile
  const int b = bbase + y;
  const size_t boff = (size_t)b * (2048 * 1024);
  const _Float16* A0 = Qh + boff + (size_t)(qt * 64) * 1024;
  const _Float16* A1 = Ql + boff + (size_t)(qt * 64) * 1024;
  const _Float16* B0 = Kh + boff + (size_t)(kt * 256) * 1024;
  const int tid = threadIdx.x;
  const int w = tid >> 6, lane = tid & 63;
  const int r16 = lane & 15, kg = lane >> 4;
  const int wn = w;  // 8 waves x 32 cols
  f32x4 acc[4][2];
  acc_zero42(acc);

  auto STAGE = [&](int t_, int buf) {
    _Float16* base_ = lds + buf * CHUNK;
    {
      int g = tid & 255;
      int row = g >> 2, c = g & 3;
      int cs = (c ^ (row >> 1)) & 3;
      const _Float16* src = (tid < 256) ? A0 : A1;
      _Float16* dst = base_ + ((tid < 256) ? 0 : 2048);
      gload_lds16(src + (size_t)row * 1024 + t_ * 32 + cs * 8, dst + g * 8);
    }
#pragma unroll
    for (int j = 0; j < 2; ++j) {
      int g = tid + j * 512;
      int row = g >> 2, c = g & 3;
      int cs = (c ^ (row >> 1)) & 3;
      gload_lds16(B0 + (size_t)row * 1024 + t_ * 32 + cs * 8,
                  base_ + 4096 + g * 8);
    }
  };
  auto COMPUTE = [&](int buf) {
    const _Float16* la = lds + buf * CHUNK;
    half8 a0[4], a1[4], bf[2];
#pragma unroll
    for (int mi = 0; mi < 4; ++mi) {
      int row = mi * 16 + r16;
      int off = row * 32 + SWZ(kg, row);
      a0[mi] = *(const half8*)(la + off);
      a1[mi] = *(const half8*)(la + 2048 + off);
    }
#pragma unroll
    for (int ni = 0; ni < 2; ++ni) {
      int row = wn * 32 + ni * 16 + r16;
      bf[ni] = *(const half8*)(la + 4096 + row * 32 + SWZ(kg, row));
    }
    __builtin_amdgcn_s_setprio(1);
#pragma unroll
    for (int mi = 0; mi < 4; ++mi)
#pragma unroll
      for (int ni = 0; ni < 2; ++ni) {
        acc[mi][ni] = __builtin_amdgcn_mfma_f32_16x16x32_f16(
            a0[mi], bf[ni], acc[mi][ni], 0, 0, 0);
        acc[mi][ni] = __builtin_amdgcn_mfma_f32_16x16x32_f16(
            a1[mi], bf[ni], acc[mi][ni], 0, 0, 0);
      }
    __builtin_amdgcn_s_setprio(0);
  };

  const int NS = 32;
  STAGE(0, 0);
  STAGE(1, 1);
  int tt = 0;
  for (; tt < NS - 1; ++tt) {
    asm volatile("s_waitcnt vmcnt(3)" ::: "memory");
    FENCED_BARRIER();
    if (tt + 2 < NS) STAGE(tt + 2, (tt + 2) % 3);
    COMPUTE(tt % 3);
  }
  asm volatile("s_waitcnt vmcnt(0)" ::: "memory");
  FENCED_BARRIER();
  COMPUTE(tt % 3);

  float* L = Lg + (size_t)y * (2048 * 2048);
#pragma unroll
  for (int mi = 0; mi < 4; ++mi) {
    int row = qt * 64 + mi * 16 + kg * 4;
#pragma unroll
    for (int ni = 0; ni < 2; ++ni) {
      int col = kt * 256 + wn * 32 + ni * 16 + r16;
#pragma unroll
      for (int j = 0; j < 4; ++j)
        L[(size_t)(row + j) * 2048 + col] = acc[mi][ni][j];
    }
  }
}

// ---------------------------------------------------------------------------
// PV: ring-3 counted-vmcnt engine, tile 128x128 (chunk 16KB, ring 48KB).
// 2 loads/thread/stage -> vmcnt(2). Causal K limit per q tile.
// ---------------------------------------------------------------------------
__global__ __launch_bounds__(512, 4) void pv_eng(
    const float* __restrict__ Lg, const _Float16* __restrict__ Vt,
    float* __restrict__ Out, int bbase) {
  extern __shared__ _Float16 lds[];
  constexpr int CHUNK = 8192;  // A 4096 | B 4096 halves
  const int id = xcd_swz(blockIdx.x, gridDim.x);
  const int y = id >> 7;
  const int qt = (id & 127) >> 3, nt = id & 7;
  const int b = bbase + y;
  const _Float16* P = (const _Float16*)(Lg + (size_t)y * (2048 * 2048));
  const _Float16* A0 = P + (size_t)(qt * 128) * 4096;
  const _Float16* B0 =
      Vt + (size_t)b * (1024 * 2048) + (size_t)(nt * 128) * 2048;
  const int NS = (qt + 1) * 4;
  const int tid = threadIdx.x;
  const int w = tid >> 6, lane = tid & 63;
  const int wm = w >> 2, wn = w & 3;
  const int r16 = lane & 15, kg = lane >> 4;
  f32x4 acc[4][2];
  acc_zero42(acc);

  auto STAGE = [&](int t_, int buf) {
    _Float16* base_ = lds + buf * CHUNK;
    {
      int row = tid >> 2, c = tid & 3;
      int cs = (c ^ (row >> 1)) & 3;
      gload_lds16(A0 + (size_t)row * 4096 + t_ * 32 + cs * 8, base_ + tid * 8);
      gload_lds16(B0 + (size_t)row * 2048 + t_ * 32 + cs * 8,
                  base_ + 4096 + tid * 8);
    }
  };
  auto COMPUTE = [&](int buf) {
    const _Float16* la = lds + buf * CHUNK;
    half8 a[4], bf[2];
#pragma unroll
    for (int mi = 0; mi < 4; ++mi) {
      int row = wm * 64 + mi * 16 + r16;
      a[mi] = *(const half8*)(la + row * 32 + SWZ(kg, row));
    }
#pragma unroll
    for (int ni = 0; ni < 2; ++ni) {
      int row = wn * 32 + ni * 16 + r16;
      bf[ni] = *(const half8*)(la + 4096 + row * 32 + SWZ(kg, row));
    }
    __builtin_amdgcn_s_setprio(1);
#pragma unroll
    for (int mi = 0; mi < 4; ++mi)
#pragma unroll
      for (int ni = 0; ni < 2; ++ni)
        acc[mi][ni] = __builtin_amdgcn_mfma_f32_16x16x32_f16(
            a[mi], bf[ni], acc[mi][ni], 0, 0, 0);
    __builtin_amdgcn_s_setprio(0);
  };

  STAGE(0, 0);
  STAGE(1, 1);
  int tt = 0;
  for (; tt < NS - 1; ++tt) {
    asm volatile("s_waitcnt vmcnt(2)" ::: "memory");
    FENCED_BARRIER();
    if (tt + 2 < NS) STAGE(tt + 2, (tt + 2) % 3);
    COMPUTE(tt % 3);
  }
  asm volatile("s_waitcnt vmcnt(0)" ::: "memory");
  FENCED_BARRIER();
  COMPUTE(tt % 3);

#pragma unroll
  for (int mi = 0; mi < 4; ++mi) {
    int row = qt * 128 + wm * 64 + mi * 16 + kg * 4;
#pragma unroll
    for (int ni = 0; ni < 2; ++ni) {
      int col = nt * 128 + wn * 32 + ni * 16 + r16;
#pragma unroll
      for (int j = 0; j < 4; ++j)
        Out[(size_t)(b * 2048 + row + j) * 1024 + col] = acc[mi][ni][j];
    }
  }
}

// ---------------------------------------------------------------------------
// Row softmax (r7-verbatim); in-place fp16 P; zero-fill to 256-col boundary.
// ---------------------------------------------------------------------------
__global__ __launch_bounds__(256) void softmax_kernel(
    float* __restrict__ Lg, const int* __restrict__ pad, int bbase) {
  const int q = blockIdx.x;
  const int y = blockIdx.y;
  const int b = bbase + y;
  const int tid = threadIdx.x;
  float* row = Lg + (size_t)y * (2048 * 2048) + (size_t)q * 2048;
  _Float16* prow = (_Float16*)row;
  const int* pb = pad + (size_t)b * 2048;
  const int kend = ((q >> 8) + 1) << 8;
  float v[8];
  int nv = 0;
  float mx = -3.0e38f;
  for (int k = tid; k <= q; k += 256) {
    float l = row[k];
    if (pb[k] == 0) l += -1.0e9f;
    v[nv++] = l;
    mx = fmaxf(mx, l);
  }
  __shared__ float red[4];
  for (int o = 32; o; o >>= 1) mx = fmaxf(mx, __shfl_xor(mx, o));
  if ((tid & 63) == 0) red[tid >> 6] = mx;
  __syncthreads();
  mx = fmaxf(fmaxf(red[0], red[1]), fmaxf(red[2], red[3]));
  __syncthreads();
  float s = 0.f;
  for (int i = 0; i < nv; ++i) s += expf(v[i] - mx);
  for (int o = 32; o; o >>= 1) s += __shfl_xor(s, o);
  if ((tid & 63) == 0) red[tid >> 6] = s;
  __syncthreads();
  s = red[0] + red[1] + red[2] + red[3];
  const float inv = 1.0f / s;
  int i = 0;
  for (int k = tid; k <= q; k += 256) {
    prow[k] = (_Float16)(expf(v[i] - mx) * inv);
    ++i;
  }
  for (int k = q + 1 + tid; k < kend; k += 256) prow[k] = (_Float16)0.0f;
}

// ---------------------------------------------------------------------------
// Fixup for degenerate rows q < f[b] (validated rounds 4-8, verbatim).
// ---------------------------------------------------------------------------
__global__ __launch_bounds__(512) void fix_f(const int* __restrict__ pad,
                                             int* __restrict__ fb) {
  const int b = threadIdx.x >> 6, k = threadIdx.x & 63;
  unsigned long long m = __ballot(pad[b * 2048 + k] != 0);
  if (k == 0) fb[b] = m ? (__ffsll((long long)m) - 1) : 64;
}

__global__ __launch_bounds__(256) void fix_qrow2(
    const float* __restrict__ xQ, const float* __restrict__ Wq,
    const float* __restrict__ bq, const int* __restrict__ fb,
    float* __restrict__ Qrow) {
  const int b = blockIdx.y;
  const int f = fb[b];
  const int tid = threadIdx.x;
  const int e = blockIdx.x * 16 + (tid >> 4);
  const int l16 = tid & 15;
  __shared__ float xq[1024];
  for (int q = 0; q < f; ++q) {
    *(f4*)&xq[tid * 4] = ((const f4*)(xQ + (size_t)(b * 2048 + q) * 1024))[tid];
    __syncthreads();
    float a = 0.f;
#pragma unroll
    for (int it = 0; it < 16; ++it) {
      int d = l16 * 4 + it * 64;
      f4 ww = *(const f4*)(Wq + (size_t)e * 1024 + d);
      a += xq[d] * ww[0] + xq[d + 1] * ww[1] + xq[d + 2] * ww[2] +
           xq[d + 3] * ww[3];
    }
    for (int o = 8; o; o >>= 1) a += __shfl_xor(a, o);
    if (l16 == 0) Qrow[((size_t)b * 64 + q) * 1024 + e] = a + bq[e];
    __syncthreads();
  }
}

__global__ __launch_bounds__(256) void fix_qb0(const float* __restrict__ bk,
                                               const int* __restrict__ fb,
                                               const float* __restrict__ Qrow,
                                               float* __restrict__ qb0) {
  const int q = blockIdx.x, b = blockIdx.y;
  if (q >= fb[b]) return;
  const int tid = threadIdx.x;
  const float* qr = Qrow + ((size_t)b * 64 + q) * 1024;
  float p = 0.f;
  for (int e = tid; e < 1024; e += 256) p += qr[e] * bk[e];
  __shared__ float red[4];
  for (int o = 32; o; o >>= 1) p += __shfl_xor(p, o);
  if ((tid & 63) == 0) red[tid >> 6] = p;
  __syncthreads();
  if (tid == 0) qb0[b * 64 + q] = red[0] + red[1] + red[2] + red[3];
}

__global__ __launch_bounds__(256) void fix_g2(const float* __restrict__ Wk,
                                              const int* __restrict__ fb,
                                              const float* __restrict__ Qrow,
                                              float* __restrict__ Gpart) {
  const int b = blockIdx.y;
  const int f = fb[b];
  const int tid = threadIdx.x;
  const int ddblk = blockIdx.x & 3, es = blockIdx.x >> 2;
  const int dd = ddblk * 256 + tid;
  __shared__ float qc[128];
  for (int q = 0; q < f; ++q) {
    if (tid < 32)
      *(f4*)&qc[tid * 4] =
          ((const f4*)(Qrow + ((size_t)b * 64 + q) * 1024 + es * 128))[tid];
    __syncthreads();
    float g = 0.f;
    for (int e = 0; e < 128; ++e)
      g += qc[e] * Wk[(size_t)(es * 128 + e) * 1024 + dd];
    Gpart[(((size_t)es * 8 + b) * 64 + q) * 1024 + dd] = g;
    __syncthreads();
  }
}

__global__ __launch_bounds__(256) void fix_logit2(
    const float* __restrict__ xK, const int* __restrict__ pad,
    const int* __restrict__ fb, const float* __restrict__ Gpart,
    const float* __restrict__ qb0, float* __restrict__ lrow) {
  const int b = blockIdx.y;
  const int f = fb[b];
  const int tid = threadIdx.x;
  const int k = blockIdx.x * 16 + (tid >> 4);
  const int l16 = tid & 15;
  __shared__ float Gs[1024];
  for (int q = 0; q < f; ++q) {
    f4 s = (f4)0.0f;
#pragma unroll
    for (int es = 0; es < 8; ++es)
      s += ((const f4*)(Gpart + (((size_t)es * 8 + b) * 64 + q) * 1024))[tid];
    *(f4*)&Gs[tid * 4] = s;
    __syncthreads();
    float a = 0.f;
#pragma unroll
    for (int it = 0; it < 16; ++it) {
      int d = l16 * 4 + it * 64;
      f4 x = *(const f4*)(xK + (size_t)(b * 2048 + k) * 1024 + d);
      a += x[0] * Gs[d] + x[1] * Gs[d + 1] + x[2] * Gs[d + 2] +
           x[3] * Gs[d + 3];
    }
    for (int o = 8; o; o >>= 1) a += __shfl_xor(a, o);
    if (l16 == 0) {
      float l = a + qb0[b * 64 + q];
      if (pad[b * 2048 + k] == 0) l += -1.0e9f;
      if (k > q) l += -1.0e9f;
      lrow[((size_t)b * 64 + q) * 2048 + k] = l;
    }
    __syncthreads();
  }
}

__global__ __launch_bounds__(256) void fix_sm(const int* __restrict__ fb,
                                              float* __restrict__ lrow,
                                              float* __restrict__ srow) {
  const int q = blockIdx.x, b = blockIdx.y;
  if (q >= fb[b]) return;
  const int tid = threadIdx.x;
  float* row = lrow + ((size_t)b * 64 + q) * 2048;
  float v[8];
  float mx = -3.0e38f;
#pragma unroll
  for (int i = 0; i < 8; ++i) {
    v[i] = row[tid + i * 256];
    mx = fmaxf(mx, v[i]);
  }
  __shared__ float red[4];
  for (int o = 32; o; o >>= 1) mx = fmaxf(mx, __shfl_xor(mx, o));
  if ((tid & 63) == 0) red[tid >> 6] = mx;
  __syncthreads();
  mx = fmaxf(fmaxf(red[0], red[1]), fmaxf(red[2], red[3]));
  __syncthreads();
  float s = 0.f;
#pragma unroll
  for (int i = 0; i < 8; ++i) {
    v[i] = expf(v[i] - mx);
    s += v[i];
  }
#pragma unroll
  for (int i = 0; i < 8; ++i) row[tid + i * 256] = v[i];
  for (int o = 32; o; o >>= 1) s += __shfl_xor(s, o);
  if ((tid & 63) == 0) red[tid >> 6] = s;
  __syncthreads();
  if (tid == 0) srow[b * 64 + q] = red[0] + red[1] + red[2] + red[3];
}

__global__ __launch_bounds__(256) void fix_pv2(
    const _Float16* __restrict__ Vt, const int* __restrict__ fb,
    const float* __restrict__ lrow, const float* __restrict__ srow,
    float* __restrict__ Out) {
  const int b = blockIdx.y;
  const int f = fb[b];
  const int tid = threadIdx.x;
  const int d = blockIdx.x * 16 + (tid >> 4);
  const int l16 = tid & 15;
  __shared__ float ps[2048];
  for (int q = 0; q < f; ++q) {
    const f4* src = (const f4*)(lrow + ((size_t)b * 64 + q) * 2048);
    *(f4*)&ps[tid * 8] = src[tid * 2];
    *(f4*)&ps[tid * 8 + 4] = src[tid * 2 + 1];
    __syncthreads();
    float o = 0.f;
#pragma unroll
    for (int it = 0; it < 16; ++it) {
      int k = l16 * 8 + it * 128;
      half8 vv = *(const half8*)(Vt + (size_t)b * (1024 * 2048) +
                                 (size_t)d * 2048 + k);
      o += (float)vv[0] * ps[k] + (float)vv[1] * ps[k + 1] +
           (float)vv[2] * ps[k + 2] + (float)vv[3] * ps[k + 3] +
           (float)vv[4] * ps[k + 4] + (float)vv[5] * ps[k + 5] +
           (float)vv[6] * ps[k + 6] + (float)vv[7] * ps[k + 7];
    }
    for (int of = 8; of; of >>= 1) o += __shfl_xor(o, of);
    if (l16 == 0)
      Out[(size_t)(b * 2048 + q) * 1024 + d] = o * (1.0f / srow[b * 64 + q]);
    __syncthreads();
  }
}

// ---------------------------------------------------------------------------
extern "C" void kernel_launch(void* const* d_in, const int* in_sizes, int n_in,
                              void* d_out, int out_size, void* d_ws,
                              size_t ws_size, hipStream_t stream) {
  const float* xQ = (const float*)d_in[0];
  const float* xK = (const float*)d_in[1];
  const float* xV = (const float*)d_in[2];
  const int* pad = (const int*)d_in[3];
  const float* Wq = (const float*)d_in[5];
  const float* bq = (const float*)d_in[6];
  const float* Wk = (const float*)d_in[7];
  const float* bk = (const float*)d_in[8];
  const float* Wv = (const float*)d_in[9];
  const float* bv = (const float*)d_in[10];
  float* Out = (float*)d_out;

  const size_t MB = (size_t)1 << 20;
  char* wsb = (char*)d_ws;
  // Persistent: Qh [0,32) Ql [32,64) Kh [64,96) Vt [96,128); Lg at 128.
  _Float16* Qh = (_Float16*)(wsb);
  _Float16* Ql = (_Float16*)(wsb + 32 * MB);
  _Float16* Kh = (_Float16*)(wsb + 64 * MB);
  _Float16* Vt = (_Float16*)(wsb + 96 * MB);
  float* Lg = (float*)(wsb + 128 * MB);

  size_t avail = (ws_size > 128 * MB) ? ws_size - 128 * MB : 0;
  int G = (int)(avail / (16 * MB));
  if (G > 8) G = 8;
  if (G < 1) G = 1;

  // W scratch (10 MB) inside the Lg region — dead before the first qk write.
  _Float16* Wqh = (_Float16*)(wsb + 128 * MB);
  _Float16* Wql = (_Float16*)(wsb + 130 * MB);
  _Float16* Wkh = (_Float16*)(wsb + 132 * MB);
  _Float16* Wkl = (_Float16*)(wsb + 134 * MB);
  _Float16* Wvh = (_Float16*)(wsb + 136 * MB);

  const int SM_P = 65536;   // proj: 2 x 32KB
  const int SM_V = 65536;   // proj V: 2 x 24KB ring + 64KB transpose
  const int SM_QK = 73728;  // 3 x 24KB
  const int SM_PV = 49152;  // 3 x 16KB
  (void)hipFuncSetAttribute((const void*)&proj_fused<1, 0>,
                            hipFuncAttributeMaxDynamicSharedMemorySize, SM_P);
  (void)hipFuncSetAttribute((const void*)&proj_fused<1, 1>,
                            hipFuncAttributeMaxDynamicSharedMemorySize, SM_P);
  (void)hipFuncSetAttribute((const void*)&proj_fused<0, 2>,
                            hipFuncAttributeMaxDynamicSharedMemorySize, SM_V);
  (void)hipFuncSetAttribute((const void*)&qk_eng,
                            hipFuncAttributeMaxDynamicSharedMemorySize, SM_QK);
  (void)hipFuncSetAttribute((const void*)&pv_eng,
                            hipFuncAttributeMaxDynamicSharedMemorySize, SM_PV);

  dim3 blk(256), eblk(512);

  // --- W conversions (tiny) ---
  cvt_split<<<dim3(1024), blk, 0, stream>>>(Wq, Wqh, Wql, 262144);
  cvt_split<<<dim3(1024), blk, 0, stream>>>(Wk, Wkh, Wkl, 262144);
  cvt_plain<<<dim3(1024), blk, 0, stream>>>(Wv, Wvh, 262144);

  // --- Projections (fused fp32->fp16 A staging; no big scratch needed) ---
  proj_fused<0, 2><<<dim3(512), eblk, SM_V, stream>>>(xV, Wvh, Wvh, bv,
                                                      nullptr, nullptr, Vt);
  proj_fused<1, 1><<<dim3(512), eblk, SM_P, stream>>>(xK, Wkh, Wkl, bk, Kh,
                                                      nullptr, nullptr);
  proj_fused<1, 0><<<dim3(512), eblk, SM_P, stream>>>(xQ, Wqh, Wql, bq, Qh, Ql,
                                                      nullptr);

  // --- Attention ---
  for (int bbase = 0; bbase < 8; bbase += G) {
    int nb = (8 - bbase < G) ? (8 - bbase) : G;
    qk_eng<<<dim3(144 * nb), eblk, SM_QK, stream>>>(Qh, Ql, Kh, Lg, bbase);
    softmax_kernel<<<dim3(2048, nb), blk, 0, stream>>>(Lg, pad, bbase);
    pv_eng<<<dim3(128 * nb), eblk, SM_PV, stream>>>(Lg, Vt, Out, bbase);
  }

  // --- Fixup: scratch in [0,24) MB (Qh dead after last qk) ---
  int* fb = (int*)(wsb);
  float* qb0 = (float*)(wsb + 4 * 1024);
  float* srow = (float*)(wsb + 8 * 1024);
  float* Qrow = (float*)(wsb + 1 * MB);   // 2 MB
  float* Gpart = (float*)(wsb + 4 * MB);  // 16 MB
  float* lrow = (float*)(wsb + 20 * MB);  // 4 MB

  fix_f<<<dim3(1), dim3(512), 0, stream>>>(pad, fb);
  fix_qrow2<<<dim3(64, 8), blk, 0, stream>>>(xQ, Wq, bq, fb, Qrow);
  fix_qb0<<<dim3(64, 8), blk, 0, stream>>>(bk, fb, Qrow, qb0);
  fix_g2<<<dim3(32, 8), blk, 0, stream>>>(Wk, fb, Qrow, Gpart);
  fix_logit2<<<dim3(128, 8), blk, 0, stream>>>(xK, pad, fb, Gpart, qb0, lrow);
  fix_sm<<<dim3(64, 8), blk, 0, stream>>>(fb, lrow, srow);
  fix_pv2<<<dim3(64, 8), blk, 0, stream>>>(Vt, fb, lrow, srow, Out);
}

// Round 10
// 496.491 us; speedup vs baseline: 1.2151x; 1.1027x over previous
//
#include <hip/hip_runtime.h>

typedef __attribute__((ext_vector_type(4))) float f4;
typedef __attribute__((ext_vector_type(4))) float f32x4;
typedef _Float16 half8 __attribute__((ext_vector_type(8)));

#define DEVI static __device__ __forceinline__

DEVI void gload_lds16(const void* g, void* l) {
  __builtin_amdgcn_global_load_lds(
      (const __attribute__((address_space(1))) void*)g,
      (__attribute__((address_space(3))) void*)l, 16, 0, 0);
}

// bijective XCD swizzle (m204)
DEVI int xcd_swz(int id, int n) {
  int q = n >> 3, r = n & 7;
  int x = id & 7, c = id >> 3;
  return (x < r ? x * (q + 1) : r * (q + 1) + (x - r) * q) + c;
}

#define FENCED_BARRIER()                \
  __builtin_amdgcn_sched_barrier(0);    \
  __builtin_amdgcn_s_barrier();         \
  __builtin_amdgcn_sched_barrier(0);

#define SWZ(kgv, rowv) ((((kgv) ^ ((rowv) >> 1)) & 3) * 8)

// ---------------------------------------------------------------------------
// fp32 -> fp16 conversions.
// ---------------------------------------------------------------------------
__global__ __launch_bounds__(256) void cvt_plain(const float* __restrict__ X,
                                                 _Float16* __restrict__ H,
                                                 int n4) {
  int i = blockIdx.x * 256 + threadIdx.x;
  const int stride = gridDim.x * 256;
  typedef _Float16 half4v __attribute__((ext_vector_type(4)));
  for (; i < n4; i += stride) {
    f4 x = ((const f4*)X)[i];
    half4v h;
#pragma unroll
    for (int j = 0; j < 4; ++j) h[j] = (_Float16)x[j];
    ((half4v*)H)[i] = h;
  }
}

__global__ __launch_bounds__(256) void cvt_split(const float* __restrict__ X,
                                                 _Float16* __restrict__ H,
                                                 _Float16* __restrict__ L,
                                                 int n4) {
  int i = blockIdx.x * 256 + threadIdx.x;
  const int stride = gridDim.x * 256;
  typedef _Float16 half4v __attribute__((ext_vector_type(4)));
  for (; i < n4; i += stride) {
    f4 x = ((const f4*)X)[i];
    half4v h, l;
#pragma unroll
    for (int j = 0; j < 4; ++j) {
      h[j] = (_Float16)x[j];
      l[j] = (_Float16)(x[j] - (float)h[j]);
    }
    ((half4v*)H)[i] = h;
    ((half4v*)L)[i] = l;
  }
}

DEVI void acc_zero44(f32x4 (&acc)[4][4]) {
#pragma unroll
  for (int i = 0; i < 4; ++i)
#pragma unroll
    for (int j = 0; j < 4; ++j) acc[i][j] = (f32x4)0.0f;
}
DEVI void acc_zero42(f32x4 (&acc)[4][2]) {
#pragma unroll
  for (int i = 0; i < 4; ++i)
#pragma unroll
    for (int j = 0; j < 2; ++j) acc[i][j] = (f32x4)0.0f;
}

// ---------------------------------------------------------------------------
// proj3: ring-3 counted-vmcnt projection engine (fast path).
// Tile 128x128, 512 thr / 8 waves (2Mx4N), wave tile 64x32 (4x2 frags).
// chunk = A(128x32) + Wh(128x32) [+ Wl(128x32)] fp16; ring-3.
// Schedule (validated structure from r9 qk/pv):
//   STAGE(0);STAGE(1); for t<NS-1 { vmcnt(L); bar; STAGE(t+2); COMPUTE(t); }
//   vmcnt(0); bar; COMPUTE(NS-1).   L = loads/thread/stage (3 or 2).
// MFMA order per chunk: a*bh then a*bl — identical to r7/r9 (bit-identical C).
// OUTMODE: 0 = Q (hi+lo out), 1 = K (hi only), 2 = V (transposed Vt store).
// ---------------------------------------------------------------------------
template <int WSPLIT, int OUTMODE>
__global__ __launch_bounds__(512, 4) void proj3(
    const _Float16* __restrict__ X, const _Float16* __restrict__ Wh,
    const _Float16* __restrict__ Wl, const float* __restrict__ bias,
    _Float16* __restrict__ OutHi, _Float16* __restrict__ OutLo,
    _Float16* __restrict__ VtOut) {
  extern __shared__ _Float16 lds[];
  constexpr int ACH = 128 * 32;
  constexpr int BCH = 128 * 32;
  constexpr int CHUNK = ACH + BCH * (1 + WSPLIT);
  const int id = xcd_swz(blockIdx.x, gridDim.x);
  const int m0 = (id >> 3) * 128, n0 = (id & 7) * 128;
  const _Float16* A0 = X + (size_t)m0 * 1024;
  const _Float16* B0 = Wh + (size_t)n0 * 1024;
  const _Float16* B1 = Wl + (size_t)n0 * 1024;
  const int tid = threadIdx.x;
  const int w = tid >> 6, lane = tid & 63;
  const int wm = w >> 2, wn = w & 3;
  const int r16 = lane & 15, kg = lane >> 4;
  f32x4 acc[4][2];
  acc_zero42(acc);

  auto STAGE = [&](int t, int buf) {
    _Float16* base = lds + buf * CHUNK;
    int row = tid >> 2, c = tid & 3;
    int cs = (c ^ (row >> 1)) & 3;
    size_t src = (size_t)row * 1024 + t * 32 + cs * 8;
    gload_lds16(A0 + src, base + tid * 8);
    gload_lds16(B0 + src, base + ACH + tid * 8);
    if (WSPLIT) gload_lds16(B1 + src, base + ACH + BCH + tid * 8);
  };
  auto COMPUTE = [&](int buf) {
    const _Float16* la = lds + buf * CHUNK;
    const _Float16* lb = la + ACH;
    half8 a[4], b0f[2], b1f[2];
#pragma unroll
    for (int mi = 0; mi < 4; ++mi) {
      int row = wm * 64 + mi * 16 + r16;
      a[mi] = *(const half8*)(la + row * 32 + SWZ(kg, row));
    }
#pragma unroll
    for (int ni = 0; ni < 2; ++ni) {
      int row = wn * 32 + ni * 16 + r16;
      int off = row * 32 + SWZ(kg, row);
      b0f[ni] = *(const half8*)(lb + off);
      if (WSPLIT) b1f[ni] = *(const half8*)(lb + BCH + off);
    }
    __builtin_amdgcn_s_setprio(1);
#pragma unroll
    for (int mi = 0; mi < 4; ++mi)
#pragma unroll
      for (int ni = 0; ni < 2; ++ni) {
        acc[mi][ni] = __builtin_amdgcn_mfma_f32_16x16x32_f16(
            a[mi], b0f[ni], acc[mi][ni], 0, 0, 0);
        if (WSPLIT)
          acc[mi][ni] = __builtin_amdgcn_mfma_f32_16x16x32_f16(
              a[mi], b1f[ni], acc[mi][ni], 0, 0, 0);
      }
    __builtin_amdgcn_s_setprio(0);
  };

  const int NS = 32;
  STAGE(0, 0);
  STAGE(1, 1);
  int tt = 0;
  for (; tt < NS - 1; ++tt) {
    if constexpr (WSPLIT)
      asm volatile("s_waitcnt vmcnt(3)" ::: "memory");
    else
      asm volatile("s_waitcnt vmcnt(2)" ::: "memory");
    FENCED_BARRIER();
    if (tt + 2 < NS) STAGE(tt + 2, (tt + 2) % 3);
    COMPUTE(tt % 3);
  }
  asm volatile("s_waitcnt vmcnt(0)" ::: "memory");
  FENCED_BARRIER();
  COMPUTE(tt % 3);

  float bcol[2];
#pragma unroll
  for (int ni = 0; ni < 2; ++ni) bcol[ni] = bias[n0 + wn * 32 + ni * 16 + r16];

  if (OUTMODE != 2) {
#pragma unroll
    for (int mi = 0; mi < 4; ++mi) {
      int row = m0 + wm * 64 + mi * 16 + kg * 4;
#pragma unroll
      for (int ni = 0; ni < 2; ++ni) {
        int col = n0 + wn * 32 + ni * 16 + r16;
#pragma unroll
        for (int j = 0; j < 4; ++j) {
          float v = acc[mi][ni][j] + bcol[ni];
          _Float16 h = (_Float16)v;
          OutHi[(size_t)(row + j) * 1024 + col] = h;
          if (OUTMODE == 0)
            OutLo[(size_t)(row + j) * 1024 + col] = (_Float16)(v - (float)h);
        }
      }
    }
  } else {
    __syncthreads();  // ring done; reuse LDS as transpose buffer (32 KB)
    _Float16(*T)[128] = (_Float16(*)[128])lds;
#pragma unroll
    for (int mi = 0; mi < 4; ++mi) {
      int ml = wm * 64 + mi * 16 + kg * 4;
#pragma unroll
      for (int ni = 0; ni < 2; ++ni) {
        int nl = wn * 32 + ni * 16 + r16;
#pragma unroll
        for (int j = 0; j < 4; ++j)
          T[nl][ml + j] = (_Float16)(acc[mi][ni][j] + bcol[ni]);
      }
    }
    __syncthreads();
    const int b = m0 >> 11;
    const int s0 = m0 & 2047;
#pragma unroll
    for (int r = 0; r < 4; ++r) {
      int flat = tid + r * 512;
      int n = flat >> 4, c = flat & 15;
      half8 v = *(const half8*)&T[n][c * 8];
      *(half8*)(VtOut + (size_t)b * (1024 * 2048) + (size_t)(n0 + n) * 2048 +
                s0 + c * 8) = v;
    }
  }
}

// ---------------------------------------------------------------------------
// Fused-cvt projection (fallback when ws is small). Validated round 9.
// ---------------------------------------------------------------------------
template <int WSPLIT, int OUTMODE>
__global__ __launch_bounds__(512, 2) void proj_fused(
    const float* __restrict__ X, const _Float16* __restrict__ Wh,
    const _Float16* __restrict__ Wl, const float* __restrict__ bias,
    _Float16* __restrict__ OutHi, _Float16* __restrict__ OutLo,
    _Float16* __restrict__ VtOut) {
  extern __shared__ _Float16 lds[];
  constexpr int ACH = 256 * 32;
  constexpr int BCH = 128 * 32;
  constexpr int CHUNK = ACH + BCH * (1 + WSPLIT);
  const int id = xcd_swz(blockIdx.x, gridDim.x);
  const int m0 = (id >> 3) * 256, n0 = (id & 7) * 128;
  const float* A = X + (size_t)m0 * 1024;
  const _Float16* B0 = Wh + (size_t)n0 * 1024;
  const _Float16* B1 = Wl + (size_t)n0 * 1024;
  const int tid = threadIdx.x;
  const int w = tid >> 6, lane = tid & 63;
  const int wm = w >> 1, wn = w & 1;
  const int r16 = lane & 15, kg = lane >> 4;
  f32x4 acc[4][4];
  acc_zero44(acc);
  f4 ra[4];

  auto ALOAD = [&](int t) {
#pragma unroll
    for (int j = 0; j < 2; ++j) {
      int g = tid + j * 512;
      int row = g >> 2, c = g & 3;
      const float* src = A + (size_t)row * 1024 + t * 32 + c * 8;
      ra[2 * j] = *(const f4*)src;
      ra[2 * j + 1] = *(const f4*)(src + 4);
    }
  };
  auto AWRITE = [&](int buf) {
    _Float16* ab = lds + buf * CHUNK;
#pragma unroll
    for (int j = 0; j < 2; ++j) {
      int g = tid + j * 512;
      int row = g >> 2, c = g & 3;
      half8 h;
#pragma unroll
      for (int e = 0; e < 4; ++e) {
        h[e] = (_Float16)ra[2 * j][e];
        h[e + 4] = (_Float16)ra[2 * j + 1][e];
      }
      *(half8*)(ab + (size_t)row * 32 + SWZ(c, row)) = h;
    }
  };
  auto WLOAD = [&](int t, int buf) {
    _Float16* bb = lds + buf * CHUNK + ACH;
    int row = tid >> 2, c = tid & 3;
    int cs = (c ^ (row >> 1)) & 3;
    gload_lds16(B0 + (size_t)row * 1024 + t * 32 + cs * 8, bb + tid * 8);
    if (WSPLIT)
      gload_lds16(B1 + (size_t)row * 1024 + t * 32 + cs * 8,
                  bb + BCH + tid * 8);
  };
  auto COMPUTE = [&](int buf) {
    const _Float16* la = lds + buf * CHUNK;
    const _Float16* lb = la + ACH;
    half8 a[4], b0f[4], b1f[4];
#pragma unroll
    for (int mi = 0; mi < 4; ++mi) {
      int row = wm * 64 + mi * 16 + r16;
      a[mi] = *(const half8*)(la + row * 32 + SWZ(kg, row));
    }
#pragma unroll
    for (int ni = 0; ni < 4; ++ni) {
      int row = wn * 64 + ni * 16 + r16;
      int off = row * 32 + SWZ(kg, row);
      b0f[ni] = *(const half8*)(lb + off);
      if (WSPLIT) b1f[ni] = *(const half8*)(lb + BCH + off);
    }
    __builtin_amdgcn_s_setprio(1);
#pragma unroll
    for (int mi = 0; mi < 4; ++mi)
#pragma unroll
      for (int ni = 0; ni < 4; ++ni) {
        acc[mi][ni] = __builtin_amdgcn_mfma_f32_16x16x32_f16(
            a[mi], b0f[ni], acc[mi][ni], 0, 0, 0);
        if (WSPLIT)
          acc[mi][ni] = __builtin_amdgcn_mfma_f32_16x16x32_f16(
              a[mi], b1f[ni], acc[mi][ni], 0, 0, 0);
      }
    __builtin_amdgcn_s_setprio(0);
  };

  const int NS = 32;
  WLOAD(0, 0);
  ALOAD(0);
  asm volatile("s_waitcnt vmcnt(0)" ::: "memory");
  __builtin_amdgcn_sched_barrier(0);
  AWRITE(0);
  asm volatile("s_waitcnt lgkmcnt(0)" ::: "memory");
  FENCED_BARRIER();
  for (int t = 0; t < NS; ++t) {
    if (t + 1 < NS) {
      WLOAD(t + 1, (t + 1) & 1);
      ALOAD(t + 1);
    }
    COMPUTE(t & 1);
    if (t + 1 < NS) {
      asm volatile("s_waitcnt vmcnt(0)" ::: "memory");
      __builtin_amdgcn_sched_barrier(0);
      AWRITE((t + 1) & 1);
      asm volatile("s_waitcnt lgkmcnt(0)" ::: "memory");
      FENCED_BARRIER();
    }
  }

  float bcol[4];
#pragma unroll
  for (int ni = 0; ni < 4; ++ni) bcol[ni] = bias[n0 + wn * 64 + ni * 16 + r16];

  if (OUTMODE != 2) {
#pragma unroll
    for (int mi = 0; mi < 4; ++mi) {
      int row = m0 + wm * 64 + mi * 16 + kg * 4;
#pragma unroll
      for (int ni = 0; ni < 4; ++ni) {
        int col = n0 + wn * 64 + ni * 16 + r16;
#pragma unroll
        for (int j = 0; j < 4; ++j) {
          float v = acc[mi][ni][j] + bcol[ni];
          _Float16 h = (_Float16)v;
          OutHi[(size_t)(row + j) * 1024 + col] = h;
          if (OUTMODE == 0)
            OutLo[(size_t)(row + j) * 1024 + col] = (_Float16)(v - (float)h);
        }
      }
    }
  } else {
    __syncthreads();
    _Float16(*T)[256] = (_Float16(*)[256])lds;
#pragma unroll
    for (int mi = 0; mi < 4; ++mi) {
      int ml = wm * 64 + mi * 16 + kg * 4;
#pragma unroll
      for (int ni = 0; ni < 4; ++ni) {
        int nl = wn * 64 + ni * 16 + r16;
#pragma unroll
        for (int j = 0; j < 4; ++j)
          T[nl][ml + j] = (_Float16)(acc[mi][ni][j] + bcol[ni]);
      }
    }
    __syncthreads();
    const int b = m0 >> 11;
    const int s0 = m0 & 2047;
#pragma unroll
    for (int r = 0; r < 8; ++r) {
      int flat = tid + r * 512;
      int n = flat >> 5, c = flat & 31;
      half8 v = *(const half8*)&T[n][c * 8];
      *(half8*)(VtOut + (size_t)b * (1024 * 2048) + (size_t)(n0 + n) * 2048 +
                s0 + c * 8) = v;
    }
  }
}

// ---------------------------------------------------------------------------
// QK^T: ring-3 counted-vmcnt engine, tile 64x256 (validated round 9).
// ---------------------------------------------------------------------------
__global__ __launch_bounds__(512, 4) void qk_eng(
    const _Float16* __restrict__ Qh, const _Float16* __restrict__ Ql,
    const _Float16* __restrict__ Kh, float* __restrict__ Lg, int bbase) {
  extern __shared__ _Float16 lds[];
  constexpr int CHUNK = 12288;  // A0 2048 | A1 2048 | B 8192 halves
  const int id = xcd_swz(blockIdx.x, gridDim.x);
  const int y = id / 144;
  int t = id % 144;
  int g4 = 0, base = 0;
  while (t >= base + (g4 + 1) * 4) { base += (g4 + 1) * 4; ++g4; }
  const int rem = t - base;
  const int qt = g4 * 4 + rem / (g4 + 1);  // 64-row q tile [0,32)
  const int kt = rem % (g4 + 1);           // 256-col k tile
  const int b = bbase + y;
  const size_t boff = (size_t)b * (2048 * 1024);
  const _Float16* A0 = Qh + boff + (size_t)(qt * 64) * 1024;
  const _Float16* A1 = Ql + boff + (size_t)(qt * 64) * 1024;
  const _Float16* B0 = Kh + boff + (size_t)(kt * 256) * 1024;
  const int tid = threadIdx.x;
  const int w = tid >> 6, lane = tid & 63;
  const int r16 = lane & 15, kg = lane >> 4;
  const int wn = w;  // 8 waves x 32 cols
  f32x4 acc[4][2];
  acc_zero42(acc);

  auto STAGE = [&](int t_, int buf) {
    _Float16* base_ = lds + buf * CHUNK;
    {
      int g = tid & 255;
      int row = g >> 2, c = g & 3;
      int cs = (c ^ (row >> 1)) & 3;
      const _Float16* src = (tid < 256) ? A0 : A1;
      _Float16* dst = base_ + ((tid < 256) ? 0 : 2048);
      gload_lds16(src + (size_t)row * 1024 + t_ * 32 + cs * 8, dst + g * 8);
    }
#pragma unroll
    for (int j = 0; j < 2; ++j) {
      int g = tid + j * 512;
      int row = g >> 2, c = g & 3;
      int cs = (c ^ (row >> 1)) & 3;
      gload_lds16(B0 + (size_t)row * 1024 + t_ * 32 + cs * 8,
                  base_ + 4096 + g * 8);
    }
  };
  auto COMPUTE = [&](int buf) {
    const _Float16* la = lds + buf * CHUNK;
    half8 a0[4], a1[4], bf[2];
#pragma unroll
    for (int mi = 0; mi < 4; ++mi) {
      int row = mi * 16 + r16;
      int off = row * 32 + SWZ(kg, row);
      a0[mi] = *(const half8*)(la + off);
      a1[mi] = *(const half8*)(la + 2048 + off);
    }
#pragma unroll
    for (int ni = 0; ni < 2; ++ni) {
      int row = wn * 32 + ni * 16 + r16;
      bf[ni] = *(const half8*)(la + 4096 + row * 32 + SWZ(kg, row));
    }
    __builtin_amdgcn_s_setprio(1);
#pragma unroll
    for (int mi = 0; mi < 4; ++mi)
#pragma unroll
      for (int ni = 0; ni < 2; ++ni) {
        acc[mi][ni] = __builtin_amdgcn_mfma_f32_16x16x32_f16(
            a0[mi], bf[ni], acc[mi][ni], 0, 0, 0);
        acc[mi][ni] = __builtin_amdgcn_mfma_f32_16x16x32_f16(
            a1[mi], bf[ni], acc[mi][ni], 0, 0, 0);
      }
    __builtin_amdgcn_s_setprio(0);
  };

  const int NS = 32;
  STAGE(0, 0);
  STAGE(1, 1);
  int tt = 0;
  for (; tt < NS - 1; ++tt) {
    asm volatile("s_waitcnt vmcnt(3)" ::: "memory");
    FENCED_BARRIER();
    if (tt + 2 < NS) STAGE(tt + 2, (tt + 2) % 3);
    COMPUTE(tt % 3);
  }
  asm volatile("s_waitcnt vmcnt(0)" ::: "memory");
  FENCED_BARRIER();
  COMPUTE(tt % 3);

  float* L = Lg + (size_t)y * (2048 * 2048);
#pragma unroll
  for (int mi = 0; mi < 4; ++mi) {
    int row = qt * 64 + mi * 16 + kg * 4;
#pragma unroll
    for (int ni = 0; ni < 2; ++ni) {
      int col = kt * 256 + wn * 32 + ni * 16 + r16;
#pragma unroll
      for (int j = 0; j < 4; ++j)
        L[(size_t)(row + j) * 2048 + col] = acc[mi][ni][j];
    }
  }
}

// ---------------------------------------------------------------------------
// PV: ring-3 counted-vmcnt engine, tile 128x128 (validated round 9).
// ---------------------------------------------------------------------------
__global__ __launch_bounds__(512, 4) void pv_eng(
    const float* __restrict__ Lg, const _Float16* __restrict__ Vt,
    float* __restrict__ Out, int bbase) {
  extern __shared__ _Float16 lds[];
  constexpr int CHUNK = 8192;  // A 4096 | B 4096 halves
  const int id = xcd_swz(blockIdx.x, gridDim.x);
  const int y = id >> 7;
  const int qt = (id & 127) >> 3, nt = id & 7;
  const int b = bbase + y;
  const _Float16* P = (const _Float16*)(Lg + (size_t)y * (2048 * 2048));
  const _Float16* A0 = P + (size_t)(qt * 128) * 4096;
  const _Float16* B0 =
      Vt + (size_t)b * (1024 * 2048) + (size_t)(nt * 128) * 2048;
  const int NS = (qt + 1) * 4;
  const int tid = threadIdx.x;
  const int w = tid >> 6, lane = tid & 63;
  const int wm = w >> 2, wn = w & 3;
  const int r16 = lane & 15, kg = lane >> 4;
  f32x4 acc[4][2];
  acc_zero42(acc);

  auto STAGE = [&](int t_, int buf) {
    _Float16* base_ = lds + buf * CHUNK;
    {
      int row = tid >> 2, c = tid & 3;
      int cs = (c ^ (row >> 1)) & 3;
      gload_lds16(A0 + (size_t)row * 4096 + t_ * 32 + cs * 8, base_ + tid * 8);
      gload_lds16(B0 + (size_t)row * 2048 + t_ * 32 + cs * 8,
                  base_ + 4096 + tid * 8);
    }
  };
  auto COMPUTE = [&](int buf) {
    const _Float16* la = lds + buf * CHUNK;
    half8 a[4], bf[2];
#pragma unroll
    for (int mi = 0; mi < 4; ++mi) {
      int row = wm * 64 + mi * 16 + r16;
      a[mi] = *(const half8*)(la + row * 32 + SWZ(kg, row));
    }
#pragma unroll
    for (int ni = 0; ni < 2; ++ni) {
      int row = wn * 32 + ni * 16 + r16;
      bf[ni] = *(const half8*)(la + 4096 + row * 32 + SWZ(kg, row));
    }
    __builtin_amdgcn_s_setprio(1);
#pragma unroll
    for (int mi = 0; mi < 4; ++mi)
#pragma unroll
      for (int ni = 0; ni < 2; ++ni)
        acc[mi][ni] = __builtin_amdgcn_mfma_f32_16x16x32_f16(
            a[mi], bf[ni], acc[mi][ni], 0, 0, 0);
    __builtin_amdgcn_s_setprio(0);
  };

  STAGE(0, 0);
  STAGE(1, 1);
  int tt = 0;
  for (; tt < NS - 1; ++tt) {
    asm volatile("s_waitcnt vmcnt(2)" ::: "memory");
    FENCED_BARRIER();
    if (tt + 2 < NS) STAGE(tt + 2, (tt + 2) % 3);
    COMPUTE(tt % 3);
  }
  asm volatile("s_waitcnt vmcnt(0)" ::: "memory");
  FENCED_BARRIER();
  COMPUTE(tt % 3);

#pragma unroll
  for (int mi = 0; mi < 4; ++mi) {
    int row = qt * 128 + wm * 64 + mi * 16 + kg * 4;
#pragma unroll
    for (int ni = 0; ni < 2; ++ni) {
      int col = nt * 128 + wn * 32 + ni * 16 + r16;
#pragma unroll
      for (int j = 0; j < 4; ++j)
        Out[(size_t)(b * 2048 + row + j) * 1024 + col] = acc[mi][ni][j];
    }
  }
}

// ---------------------------------------------------------------------------
// Row softmax; in-place fp16 P; zero-fill to 256-col boundary.
// ---------------------------------------------------------------------------
__global__ __launch_bounds__(256) void softmax_kernel(
    float* __restrict__ Lg, const int* __restrict__ pad, int bbase) {
  const int q = blockIdx.x;
  const int y = blockIdx.y;
  const int b = bbase + y;
  const int tid = threadIdx.x;
  float* row = Lg + (size_t)y * (2048 * 2048) + (size_t)q * 2048;
  _Float16* prow = (_Float16*)row;
  const int* pb = pad + (size_t)b * 2048;
  const int kend = ((q >> 8) + 1) << 8;
  float v[8];
  int nv = 0;
  float mx = -3.0e38f;
  for (int k = tid; k <= q; k += 256) {
    float l = row[k];
    if (pb[k] == 0) l += -1.0e9f;
    v[nv++] = l;
    mx = fmaxf(mx, l);
  }
  __shared__ float red[4];
  for (int o = 32; o; o >>= 1) mx = fmaxf(mx, __shfl_xor(mx, o));
  if ((tid & 63) == 0) red[tid >> 6] = mx;
  __syncthreads();
  mx = fmaxf(fmaxf(red[0], red[1]), fmaxf(red[2], red[3]));
  __syncthreads();
  float s = 0.f;
  for (int i = 0; i < nv; ++i) s += expf(v[i] - mx);
  for (int o = 32; o; o >>= 1) s += __shfl_xor(s, o);
  if ((tid & 63) == 0) red[tid >> 6] = s;
  __syncthreads();
  s = red[0] + red[1] + red[2] + red[3];
  const float inv = 1.0f / s;
  int i = 0;
  for (int k = tid; k <= q; k += 256) {
    prow[k] = (_Float16)(expf(v[i] - mx) * inv);
    ++i;
  }
  for (int k = q + 1 + tid; k < kend; k += 256) prow[k] = (_Float16)0.0f;
}

// ---------------------------------------------------------------------------
// Fixup for degenerate rows q < f[b] (validated rounds 4-9, verbatim).
// ---------------------------------------------------------------------------
__global__ __launch_bounds__(512) void fix_f(const int* __restrict__ pad,
                                             int* __restrict__ fb) {
  const int b = threadIdx.x >> 6, k = threadIdx.x & 63;
  unsigned long long m = __ballot(pad[b * 2048 + k] != 0);
  if (k == 0) fb[b] = m ? (__ffsll((long long)m) - 1) : 64;
}

__global__ __launch_bounds__(256) void fix_qrow2(
    const float* __restrict__ xQ, const float* __restrict__ Wq,
    const float* __restrict__ bq, const int* __restrict__ fb,
    float* __restrict__ Qrow) {
  const int b = blockIdx.y;
  const int f = fb[b];
  const int tid = threadIdx.x;
  const int e = blockIdx.x * 16 + (tid >> 4);
  const int l16 = tid & 15;
  __shared__ float xq[1024];
  for (int q = 0; q < f; ++q) {
    *(f4*)&xq[tid * 4] = ((const f4*)(xQ + (size_t)(b * 2048 + q) * 1024))[tid];
    __syncthreads();
    float a = 0.f;
#pragma unroll
    for (int it = 0; it < 16; ++it) {
      int d = l16 * 4 + it * 64;
      f4 ww = *(const f4*)(Wq + (size_t)e * 1024 + d);
      a += xq[d] * ww[0] + xq[d + 1] * ww[1] + xq[d + 2] * ww[2] +
           xq[d + 3] * ww[3];
    }
    for (int o = 8; o; o >>= 1) a += __shfl_xor(a, o);
    if (l16 == 0) Qrow[((size_t)b * 64 + q) * 1024 + e] = a + bq[e];
    __syncthreads();
  }
}

__global__ __launch_bounds__(256) void fix_qb0(const float* __restrict__ bk,
                                               const int* __restrict__ fb,
                                               const float* __restrict__ Qrow,
                                               float* __restrict__ qb0) {
  const int q = blockIdx.x, b = blockIdx.y;
  if (q >= fb[b]) return;
  const int tid = threadIdx.x;
  const float* qr = Qrow + ((size_t)b * 64 + q) * 1024;
  float p = 0.f;
  for (int e = tid; e < 1024; e += 256) p += qr[e] * bk[e];
  __shared__ float red[4];
  for (int o = 32; o; o >>= 1) p += __shfl_xor(p, o);
  if ((tid & 63) == 0) red[tid >> 6] = p;
  __syncthreads();
  if (tid == 0) qb0[b * 64 + q] = red[0] + red[1] + red[2] + red[3];
}

__global__ __launch_bounds__(256) void fix_g2(const float* __restrict__ Wk,
                                              const int* __restrict__ fb,
                                              const float* __restrict__ Qrow,
                                              float* __restrict__ Gpart) {
  const int b = blockIdx.y;
  const int f = fb[b];
  const int tid = threadIdx.x;
  const int ddblk = blockIdx.x & 3, es = blockIdx.x >> 2;
  const int dd = ddblk * 256 + tid;
  __shared__ float qc[128];
  for (int q = 0; q < f; ++q) {
    if (tid < 32)
      *(f4*)&qc[tid * 4] =
          ((const f4*)(Qrow + ((size_t)b * 64 + q) * 1024 + es * 128))[tid];
    __syncthreads();
    float g = 0.f;
    for (int e = 0; e < 128; ++e)
      g += qc[e] * Wk[(size_t)(es * 128 + e) * 1024 + dd];
    Gpart[(((size_t)es * 8 + b) * 64 + q) * 1024 + dd] = g;
    __syncthreads();
  }
}

__global__ __launch_bounds__(256) void fix_logit2(
    const float* __restrict__ xK, const int* __restrict__ pad,
    const int* __restrict__ fb, const float* __restrict__ Gpart,
    const float* __restrict__ qb0, float* __restrict__ lrow) {
  const int b = blockIdx.y;
  const int f = fb[b];
  const int tid = threadIdx.x;
  const int k = blockIdx.x * 16 + (tid >> 4);
  const int l16 = tid & 15;
  __shared__ float Gs[1024];
  for (int q = 0; q < f; ++q) {
    f4 s = (f4)0.0f;
#pragma unroll
    for (int es = 0; es < 8; ++es)
      s += ((const f4*)(Gpart + (((size_t)es * 8 + b) * 64 + q) * 1024))[tid];
    *(f4*)&Gs[tid * 4] = s;
    __syncthreads();
    float a = 0.f;
#pragma unroll
    for (int it = 0; it < 16; ++it) {
      int d = l16 * 4 + it * 64;
      f4 x = *(const f4*)(xK + (size_t)(b * 2048 + k) * 1024 + d);
      a += x[0] * Gs[d] + x[1] * Gs[d + 1] + x[2] * Gs[d + 2] +
           x[3] * Gs[d + 3];
    }
    for (int o = 8; o; o >>= 1) a += __shfl_xor(a, o);
    if (l16 == 0) {
      float l = a + qb0[b * 64 + q];
      if (pad[b * 2048 + k] == 0) l += -1.0e9f;
      if (k > q) l += -1.0e9f;
      lrow[((size_t)b * 64 + q) * 2048 + k] = l;
    }
    __syncthreads();
  }
}

__global__ __launch_bounds__(256) void fix_sm(const int* __restrict__ fb,
                                              float* __restrict__ lrow,
                                              float* __restrict__ srow) {
  const int q = blockIdx.x, b = blockIdx.y;
  if (q >= fb[b]) return;
  const int tid = threadIdx.x;
  float* row = lrow + ((size_t)b * 64 + q) * 2048;
  float v[8];
  float mx = -3.0e38f;
#pragma unroll
  for (int i = 0; i < 8; ++i) {
    v[i] = row[tid + i * 256];
    mx = fmaxf(mx, v[i]);
  }
  __shared__ float red[4];
  for (int o = 32; o; o >>= 1) mx = fmaxf(mx, __shfl_xor(mx, o));
  if ((tid & 63) == 0) red[tid >> 6] = mx;
  __syncthreads();
  mx = fmaxf(fmaxf(red[0], red[1]), fmaxf(red[2], red[3]));
  __syncthreads();
  float s = 0.f;
#pragma unroll
  for (int i = 0; i < 8; ++i) {
    v[i] = expf(v[i] - mx);
    s += v[i];
  }
#pragma unroll
  for (int i = 0; i < 8; ++i) row[tid + i * 256] = v[i];
  for (int o = 32; o; o >>= 1) s += __shfl_xor(s, o);
  if ((tid & 63) == 0) red[tid >> 6] = s;
  __syncthreads();
  if (tid == 0) srow[b * 64 + q] = red[0] + red[1] + red[2] + red[3];
}

__global__ __launch_bounds__(256) void fix_pv2(
    const _Float16* __restrict__ Vt, const int* __restrict__ fb,
    const float* __restrict__ lrow, const float* __restrict__ srow,
    float* __restrict__ Out) {
  const int b = blockIdx.y;
  const int f = fb[b];
  const int tid = threadIdx.x;
  const int d = blockIdx.x * 16 + (tid >> 4);
  const int l16 = tid & 15;
  __shared__ float ps[2048];
  for (int q = 0; q < f; ++q) {
    const f4* src = (const f4*)(lrow + ((size_t)b * 64 + q) * 2048);
    *(f4*)&ps[tid * 8] = src[tid * 2];
    *(f4*)&ps[tid * 8 + 4] = src[tid * 2 + 1];
    __syncthreads();
    float o = 0.f;
#pragma unroll
    for (int it = 0; it < 16; ++it) {
      int k = l16 * 8 + it * 128;
      half8 vv = *(const half8*)(Vt + (size_t)b * (1024 * 2048) +
                                 (size_t)d * 2048 + k);
      o += (float)vv[0] * ps[k] + (float)vv[1] * ps[k + 1] +
           (float)vv[2] * ps[k + 2] + (float)vv[3] * ps[k + 3] +
           (float)vv[4] * ps[k + 4] + (float)vv[5] * ps[k + 5] +
           (float)vv[6] * ps[k + 6] + (float)vv[7] * ps[k + 7];
    }
    for (int of = 8; of; of >>= 1) o += __shfl_xor(o, of);
    if (l16 == 0)
      Out[(size_t)(b * 2048 + q) * 1024 + d] = o * (1.0f / srow[b * 64 + q]);
    __syncthreads();
  }
}

// ---------------------------------------------------------------------------
extern "C" void kernel_launch(void* const* d_in, const int* in_sizes, int n_in,
                              void* d_out, int out_size, void* d_ws,
                              size_t ws_size, hipStream_t stream) {
  const float* xQ = (const float*)d_in[0];
  const float* xK = (const float*)d_in[1];
  const float* xV = (const float*)d_in[2];
  const int* pad = (const int*)d_in[3];
  const float* Wq = (const float*)d_in[5];
  const float* bq = (const float*)d_in[6];
  const float* Wk = (const float*)d_in[7];
  const float* bk = (const float*)d_in[8];
  const float* Wv = (const float*)d_in[9];
  const float* bv = (const float*)d_in[10];
  float* Out = (float*)d_out;

  const size_t MB = (size_t)1 << 20;
  char* wsb = (char*)d_ws;
  // Persistent: Qh [0,32) Ql [32,64) Kh [64,96) Vt [96,128); Lg at 128.
  _Float16* Qh = (_Float16*)(wsb);
  _Float16* Ql = (_Float16*)(wsb + 32 * MB);
  _Float16* Kh = (_Float16*)(wsb + 64 * MB);
  _Float16* Vt = (_Float16*)(wsb + 96 * MB);
  float* Lg = (float*)(wsb + 128 * MB);

  size_t avail = (ws_size > 128 * MB) ? ws_size - 128 * MB : 0;
  int G = (int)(avail / (16 * MB));
  if (G > 8) G = 8;
  if (G < 1) G = 1;

  const int SM_P1 = 73728;  // proj3 WSPLIT=1: 3 x 24KB
  const int SM_P0 = 49152;  // proj3 WSPLIT=0: 3 x 16KB (+32KB transpose fits)
  const int SM_F = 65536;   // proj_fused fallback
  const int SM_QK = 73728;  // 3 x 24KB
  const int SM_PV = 49152;  // 3 x 16KB
  (void)hipFuncSetAttribute((const void*)&proj3<1, 0>,
                            hipFuncAttributeMaxDynamicSharedMemorySize, SM_P1);
  (void)hipFuncSetAttribute((const void*)&proj3<1, 1>,
                            hipFuncAttributeMaxDynamicSharedMemorySize, SM_P1);
  (void)hipFuncSetAttribute((const void*)&proj3<0, 2>,
                            hipFuncAttributeMaxDynamicSharedMemorySize, SM_P0);
  (void)hipFuncSetAttribute((const void*)&proj_fused<1, 0>,
                            hipFuncAttributeMaxDynamicSharedMemorySize, SM_F);
  (void)hipFuncSetAttribute((const void*)&proj_fused<1, 1>,
                            hipFuncAttributeMaxDynamicSharedMemorySize, SM_F);
  (void)hipFuncSetAttribute((const void*)&proj_fused<0, 2>,
                            hipFuncAttributeMaxDynamicSharedMemorySize, SM_F);
  (void)hipFuncSetAttribute((const void*)&qk_eng,
                            hipFuncAttributeMaxDynamicSharedMemorySize, SM_QK);
  (void)hipFuncSetAttribute((const void*)&pv_eng,
                            hipFuncAttributeMaxDynamicSharedMemorySize, SM_PV);

  dim3 blk(256), eblk(512);

  if (ws_size >= 165 * MB) {
    // Fast path: pre-convert X (scratch in dead regions) + ring-3 proj3.
    // V: sXv@[0,32) (Qh region), Wvh@[32,34) (Ql region).
    {
      _Float16* sX = (_Float16*)(wsb);
      _Float16* sW = (_Float16*)(wsb + 32 * MB);
      cvt_plain<<<dim3(2048), blk, 0, stream>>>(xV, sX, 4194304);
      cvt_plain<<<dim3(1024), blk, 0, stream>>>(Wv, sW, 262144);
      proj3<0, 2><<<dim3(1024), eblk, SM_P0, stream>>>(sX, sW, sW, bv, nullptr,
                                                       nullptr, Vt);
    }
    // K: sXk@[0,32), Wkh@[32,34), Wkl@[34,36). Writes Kh@[64,96).
    {
      _Float16* sX = (_Float16*)(wsb);
      _Float16* sWh = (_Float16*)(wsb + 32 * MB);
      _Float16* sWl = (_Float16*)(wsb + 34 * MB);
      cvt_plain<<<dim3(2048), blk, 0, stream>>>(xK, sX, 4194304);
      cvt_split<<<dim3(1024), blk, 0, stream>>>(Wk, sWh, sWl, 262144);
      proj3<1, 1><<<dim3(1024), eblk, SM_P1, stream>>>(sX, sWh, sWl, bk, Kh,
                                                       nullptr, nullptr);
    }
    // Q: sXq@[128,160) (Lg region), Wqh@[160,162), Wql@[162,164).
    // Writes Qh@[0,32) + Ql@[32,64).
    {
      _Float16* sX = (_Float16*)(wsb + 128 * MB);
      _Float16* sWh = (_Float16*)(wsb + 160 * MB);
      _Float16* sWl = (_Float16*)(wsb + 162 * MB);
      cvt_plain<<<dim3(2048), blk, 0, stream>>>(xQ, sX, 4194304);
      cvt_split<<<dim3(1024), blk, 0, stream>>>(Wq, sWh, sWl, 262144);
      proj3<1, 0><<<dim3(1024), eblk, SM_P1, stream>>>(sX, sWh, sWl, bq, Qh,
                                                       Ql, nullptr);
    }
  } else {
    // Fallback (validated round 9): fused-cvt projections, W scratch in Lg.
    _Float16* Wqh = (_Float16*)(wsb + 128 * MB);
    _Float16* Wql = (_Float16*)(wsb + 130 * MB);
    _Float16* Wkh = (_Float16*)(wsb + 132 * MB);
    _Float16* Wkl = (_Float16*)(wsb + 134 * MB);
    _Float16* Wvh = (_Float16*)(wsb + 136 * MB);
    cvt_split<<<dim3(1024), blk, 0, stream>>>(Wq, Wqh, Wql, 262144);
    cvt_split<<<dim3(1024), blk, 0, stream>>>(Wk, Wkh, Wkl, 262144);
    cvt_plain<<<dim3(1024), blk, 0, stream>>>(Wv, Wvh, 262144);
    proj_fused<0, 2><<<dim3(512), eblk, SM_F, stream>>>(xV, Wvh, Wvh, bv,
                                                        nullptr, nullptr, Vt);
    proj_fused<1, 1><<<dim3(512), eblk, SM_F, stream>>>(xK, Wkh, Wkl, bk, Kh,
                                                        nullptr, nullptr);
    proj_fused<1, 0><<<dim3(512), eblk, SM_F, stream>>>(xQ, Wqh, Wql, bq, Qh,
                                                        Ql, nullptr);
  }

  // --- Attention ---
  for (int bbase = 0; bbase < 8; bbase += G) {
    int nb = (8 - bbase < G) ? (8 - bbase) : G;
    qk_eng<<<dim3(144 * nb), eblk, SM_QK, stream>>>(Qh, Ql, Kh, Lg, bbase);
    softmax_kernel<<<dim3(2048, nb), blk, 0, stream>>>(Lg, pad, bbase);
    pv_eng<<<dim3(128 * nb), eblk, SM_PV, stream>>>(Lg, Vt, Out, bbase);
  }

  // --- Fixup: scratch in [0,24) MB (Qh dead after last qk) ---
  int* fb = (int*)(wsb);
  float* qb0 = (float*)(wsb + 4 * 1024);
  float* srow = (float*)(wsb + 8 * 1024);
  float* Qrow = (float*)(wsb + 1 * MB);   // 2 MB
  float* Gpart = (float*)(wsb + 4 * MB);  // 16 MB
  float* lrow = (float*)(wsb + 20 * MB);  // 4 MB

  fix_f<<<dim3(1), dim3(512), 0, stream>>>(pad, fb);
  fix_qrow2<<<dim3(64, 8), blk, 0, stream>>>(xQ, Wq, bq, fb, Qrow);
  fix_qb0<<<dim3(64, 8), blk, 0, stream>>>(bk, fb, Qrow, qb0);
  fix_g2<<<dim3(32, 8), blk, 0, stream>>>(Wk, fb, Qrow, Gpart);
  fix_logit2<<<dim3(128, 8), blk, 0, stream>>>(xK, pad, fb, Gpart, qb0, lrow);
  fix_sm<<<dim3(64, 8), blk, 0, stream>>>(fb, lrow, srow);
  fix_pv2<<<dim3(64, 8), blk, 0, stream>>>(Vt, fb, lrow, srow, Out);
}